// Round 8
// baseline (2701.754 us; speedup 1.0000x reference)
//
#include <hip/hip_runtime.h>
#include <hip/hip_fp16.h>

#define N_NODES 50000
#define N_EDGES 800000
#define D_IN_K  500
#define H_DIM   256
#define N_CLS   7
#define ALPHA_W 0.5f
#define GAMMA_W 0.5f
#define EPS_W   0.1f
#define LN_EPS_W 1e-5f

typedef unsigned short u16;
typedef unsigned int   u32;

// fp16 storage <-> fp32 compute
__device__ __forceinline__ float h2f(u16 v) {
    __half h;
    *reinterpret_cast<u16*>(&h) = v;
    return __half2float(h);
}
__device__ __forceinline__ u16 f2h(float f) {
    __half h = __float2half_rn(f);
    return *reinterpret_cast<u16*>(&h);
}
__device__ __forceinline__ int clampN(int v) {
    return (v < 0) ? 0 : ((v >= N_NODES) ? N_NODES - 1 : v);
}

// ---------------- fallback sentinel (fp32 output) ----------------
__global__ __launch_bounds__(256) void sentinel_kernel(float* out, int n) {
    int i = blockIdx.x * blockDim.x + threadIdx.x;
    if (i < n) out[i] = 2.0f;
}

// ---------------- CSR build ----------------
__global__ __launch_bounds__(256) void zero_kernel(int* p, int n) {
    int i = blockIdx.x * blockDim.x + threadIdx.x;
    if (i < n) p[i] = 0;
}

__global__ __launch_bounds__(256) void hist_kernel(const int* __restrict__ dst, int* __restrict__ deg, int e) {
    int i = blockIdx.x * blockDim.x + threadIdx.x;
    if (i < e) atomicAdd(&deg[clampN(dst[i])], 1);
}

__global__ __launch_bounds__(1024) void scan_kernel(const int* __restrict__ deg, int* __restrict__ row_ptr, int n) {
    __shared__ int sdata[1024];
    __shared__ int carry;
    int t = threadIdx.x;
    if (t == 0) carry = 0;
    for (int base = 0; base < n; base += 1024) {
        int i = base + t;
        int v = (i < n) ? deg[i] : 0;
        __syncthreads();
        sdata[t] = v;
        __syncthreads();
        for (int off = 1; off < 1024; off <<= 1) {
            int a = (t >= off) ? sdata[t - off] : 0;
            __syncthreads();
            sdata[t] += a;
            __syncthreads();
        }
        int incl = sdata[t];
        int c = carry;
        if (i < n) row_ptr[i] = c + incl - v;   // exclusive
        int total = sdata[1023];
        __syncthreads();
        if (t == 0) carry = c + total;
    }
    __syncthreads();
    if (t == 0) row_ptr[n] = carry;
}

__global__ __launch_bounds__(256) void scatter_kernel(const int* __restrict__ src, const int* __restrict__ dst,
                                                      const int* __restrict__ row_ptr, int* __restrict__ deg,
                                                      int* __restrict__ srcS, int e) {
    int i = blockIdx.x * blockDim.x + threadIdx.x;
    if (i < e) {
        int d = clampN(dst[i]);
        int old = atomicSub(&deg[d], 1);
        int pos = row_ptr[d] + old - 1;
        if (pos >= 0 && pos < e) srcS[pos] = clampN(src[i]);
    }
}

// ---------------- init GEMM (simple): x0 = X @ W^T + b  (fp32 in, fp16 out) ----------------
__global__ __launch_bounds__(256) void init_gemm_simple(const float* __restrict__ X,
                                                        const float* __restrict__ W,
                                                        const float* __restrict__ bias,
                                                        u16* __restrict__ out) {
    __shared__ float xrow[D_IN_K];
    int n = blockIdx.x;
    int t = threadIdx.x;
    const float* xp = X + (long)n * D_IN_K;
    for (int i = t; i < D_IN_K; i += 256) xrow[i] = xp[i];
    __syncthreads();
    const float* wp = W + (long)t * D_IN_K;
    float acc = 0.f;
    for (int k = 0; k < D_IN_K; k++) acc = fmaf(xrow[k], wp[k], acc);
    out[(long)n * H_DIM + t] = f2h(acc + bias[t]);
}

// ---------------- per-layer: al/ar projections ----------------
__global__ __launch_bounds__(256) void alar_kernel(const u16* __restrict__ x,
                                                   const float* __restrict__ attl,
                                                   const float* __restrict__ attr,
                                                   float* __restrict__ al, float* __restrict__ ar, int n) {
    int w = (blockIdx.x * blockDim.x + threadIdx.x) >> 6;
    int lane = threadIdx.x & 63;
    if (w >= n) return;
    int col = lane * 4;
    ushort4 xv = *(const ushort4*)(x + (long)w * H_DIM + col);
    float4 lv = *(const float4*)(attl + col);
    float4 rv = *(const float4*)(attr + col);
    float x0 = h2f(xv.x), x1 = h2f(xv.y), x2 = h2f(xv.z), x3 = h2f(xv.w);
    float pl = x0 * lv.x + x1 * lv.y + x2 * lv.z + x3 * lv.w;
    float pr = x0 * rv.x + x1 * rv.y + x2 * rv.z + x3 * rv.w;
#pragma unroll
    for (int off = 32; off >= 1; off >>= 1) {
        pl += __shfl_xor(pl, off);
        pr += __shfl_xor(pr, off);
    }
    if (lane == 0) { al[w] = pl; ar[w] = pr; }
}

// ---------------- per-layer: scalar gather + self-loop + eps*x0 + relu/LN ----------------
__global__ __launch_bounds__(256) void layer_kernel(const u16* __restrict__ xin,
                                                    const u16* __restrict__ x0,
                                                    const float* __restrict__ al,
                                                    const float* __restrict__ ar,
                                                    const int* __restrict__ row_ptr,
                                                    const int* __restrict__ srcS,
                                                    const float* __restrict__ g,
                                                    const float* __restrict__ b,
                                                    u16* __restrict__ xout, int n, int do_ln) {
    int w = (blockIdx.x * blockDim.x + threadIdx.x) >> 6;
    int lane = threadIdx.x & 63;
    if (w >= n) return;
    int col = lane * 4;

    float arn = ar[w];
    float aself = ALPHA_W * tanhf(al[w] + arn);

    ushort4 xs = *(const ushort4*)(xin + (long)w * H_DIM + col);
    float a0 = aself * h2f(xs.x);
    float a1 = aself * h2f(xs.y);
    float a2 = aself * h2f(xs.z);
    float a3 = aself * h2f(xs.w);

    ushort4 x0v = *(const ushort4*)(x0 + (long)w * H_DIM + col);
    a0 += EPS_W * h2f(x0v.x);
    a1 += EPS_W * h2f(x0v.y);
    a2 += EPS_W * h2f(x0v.z);
    a3 += EPS_W * h2f(x0v.w);

    int e0 = row_ptr[w], e1 = row_ptr[w + 1];
    for (int e = e0; e < e1; e++) {
        int s = clampN(srcS[e]);                       // uniform load (broadcast)
        float aj = GAMMA_W * tanhf(al[s] + arn);
        ushort4 xv = *(const ushort4*)(xin + (long)s * H_DIM + col);
        a0 = fmaf(aj, h2f(xv.x), a0);
        a1 = fmaf(aj, h2f(xv.y), a1);
        a2 = fmaf(aj, h2f(xv.z), a2);
        a3 = fmaf(aj, h2f(xv.w), a3);
    }

    ushort4 o;
    if (do_ln) {
        float v0 = fmaxf(a0, 0.f), v1 = fmaxf(a1, 0.f), v2 = fmaxf(a2, 0.f), v3 = fmaxf(a3, 0.f);
        float sum = v0 + v1 + v2 + v3;
        float sq = v0 * v0 + v1 * v1 + v2 * v2 + v3 * v3;
#pragma unroll
        for (int off = 32; off >= 1; off >>= 1) {
            sum += __shfl_xor(sum, off);
            sq += __shfl_xor(sq, off);
        }
        float mu = sum * (1.f / 256.f);
        float var = sq * (1.f / 256.f) - mu * mu;
        var = fmaxf(var, 0.f);
        float rstd = rsqrtf(var + LN_EPS_W);
        float4 g4 = *(const float4*)(g + col);
        float4 b4 = *(const float4*)(b + col);
        o.x = f2h((v0 - mu) * rstd * g4.x + b4.x);
        o.y = f2h((v1 - mu) * rstd * g4.y + b4.y);
        o.z = f2h((v2 - mu) * rstd * g4.z + b4.z);
        o.w = f2h((v3 - mu) * rstd * g4.w + b4.w);
    } else {
        o.x = f2h(a0); o.y = f2h(a1); o.z = f2h(a2); o.w = f2h(a3);
    }
    *(ushort4*)(xout + (long)w * H_DIM + col) = o;
}

// ---------------- final: emb = x @ W_last^T + b_last ; log_softmax (fp32 OUT) ----------------
__global__ __launch_bounds__(256) void final_kernel(const u16* __restrict__ x,
                                                    const float* __restrict__ Wl,
                                                    const float* __restrict__ bl,
                                                    float* __restrict__ out, int n) {
    __shared__ float Ws[N_CLS * H_DIM];
    for (int i = threadIdx.x; i < N_CLS * H_DIM; i += blockDim.x) Ws[i] = Wl[i];
    __syncthreads();

    int w = (blockIdx.x * blockDim.x + threadIdx.x) >> 6;
    int lane = threadIdx.x & 63;
    if (w >= n) return;
    int col = lane * 4;
    ushort4 xv = *(const ushort4*)(x + (long)w * H_DIM + col);
    float x0 = h2f(xv.x), x1 = h2f(xv.y), x2 = h2f(xv.z), x3 = h2f(xv.w);

    float p[N_CLS];
#pragma unroll
    for (int c = 0; c < N_CLS; c++) {
        const float* wr = &Ws[c * H_DIM + col];
        p[c] = x0 * wr[0] + x1 * wr[1] + x2 * wr[2] + x3 * wr[3];
    }
#pragma unroll
    for (int off = 32; off >= 1; off >>= 1) {
#pragma unroll
        for (int c = 0; c < N_CLS; c++) p[c] += __shfl_xor(p[c], off);
    }
    if (lane == 0) {
        float e[N_CLS];
        float m = -1e30f;
#pragma unroll
        for (int c = 0; c < N_CLS; c++) {
            e[c] = p[c] + bl[c];
            m = fmaxf(m, e[c]);
        }
        float s = 0.f;
#pragma unroll
        for (int c = 0; c < N_CLS; c++) s += expf(e[c] - m);
        float lse = logf(s);
#pragma unroll
        for (int c = 0; c < N_CLS; c++) {
            out[(long)w * N_CLS + c] = e[c];
            out[(long)N_NODES * N_CLS + (long)w * N_CLS + c] = e[c] - m - lse;
        }
    }
}

extern "C" void kernel_launch(void* const* d_in, const int* in_sizes, int n_in,
                              void* d_out, int out_size, void* d_ws, size_t ws_size,
                              hipStream_t stream) {
    const float* x_in   = (const float*)d_in[0];
    const int*   ei     = (const int*)d_in[1];     // [2][E] planar int32
    const float* W_init = (const float*)d_in[2];
    const float* b_init = (const float*)d_in[3];
    const float* att_l  = (const float*)d_in[4];
    const float* att_r  = (const float*)d_in[5];
    const float* ln_g   = (const float*)d_in[6];
    const float* ln_b   = (const float*)d_in[7];
    const float* W_last = (const float*)d_in[8];
    const float* b_last = (const float*)d_in[9];
    float* out = (float*)d_out;                    // fp32 output

    // workspace layout (80,800,064 B total); x buffers are fp16 now
    const size_t OFF_X0  = 0;                  // 25,600,000
    const size_t OFF_XA  = 25600000;           // 25,600,000
    const size_t OFF_XB  = 51200000;           // 25,600,000
    const size_t OFF_AL  = 76800000;           //    200,000
    const size_t OFF_AR  = 77000000;           //    200,000
    const size_t OFF_DEG = 77200000;           //    200,000
    const size_t OFF_RP  = 77400000;           //    200,064
    const size_t OFF_SRC = 77600064;           //  3,200,000
    const size_t WS_NEED = 80800064;

    if (ws_size < WS_NEED) {
        sentinel_kernel<<<(out_size + 255) / 256, 256, 0, stream>>>(out, out_size);
        return;
    }

    char* ws = (char*)d_ws;
    u16* x0  = (u16*)(ws + OFF_X0);
    u16* xA  = (u16*)(ws + OFF_XA);
    u16* xB  = (u16*)(ws + OFF_XB);
    float* al = (float*)(ws + OFF_AL);
    float* ar = (float*)(ws + OFF_AR);
    int* deg     = (int*)(ws + OFF_DEG);
    int* row_ptr = (int*)(ws + OFF_RP);
    int* srcS    = (int*)(ws + OFF_SRC);

    const int* e_src = ei;
    const int* e_dst = ei + N_EDGES;

    // --- CSR build (by dst) ---
    int zb = (N_NODES + 255) / 256;
    zero_kernel<<<zb, 256, 0, stream>>>(deg, N_NODES);
    int eb = (N_EDGES + 255) / 256;
    hist_kernel<<<eb, 256, 0, stream>>>(e_dst, deg, N_EDGES);
    scan_kernel<<<1, 1024, 0, stream>>>(deg, row_ptr, N_NODES);
    scatter_kernel<<<eb, 256, 0, stream>>>(e_src, e_dst, row_ptr, deg, srcS, N_EDGES);

    // --- init linear (simple) ---
    init_gemm_simple<<<N_NODES, 256, 0, stream>>>(x_in, W_init, b_init, x0);

    // --- layers ---
    int nb = (N_NODES * 64 + 255) / 256;   // one wave per node
    const u16* bufs_in[4]  = {x0, xA, xB, xA};
    u16* bufs_out[4]       = {xA, xB, xA, xB};
    for (int i = 0; i < 4; i++) {
        const u16* xin = bufs_in[i];
        u16* xout = bufs_out[i];
        alar_kernel<<<nb, 256, 0, stream>>>(xin, att_l + i * H_DIM, att_r + i * H_DIM, al, ar, N_NODES);
        layer_kernel<<<nb, 256, 0, stream>>>(xin, x0, al, ar, row_ptr, srcS,
                                             ln_g + i * H_DIM, ln_b + i * H_DIM,
                                             xout, N_NODES, (i < 3) ? 1 : 0);
    }

    // --- final linear + log_softmax ---
    final_kernel<<<nb, 256, 0, stream>>>(xB, W_last, b_last, out, N_NODES);
}

// Round 9
// 1033.769 us; speedup vs baseline: 2.6135x; 2.6135x over previous
//
#include <hip/hip_runtime.h>
#include <hip/hip_fp16.h>

#define N_NODES 50000
#define N_EDGES 800000
#define D_IN_K  500
#define H_DIM   256
#define N_CLS   7
#define ALPHA_W 0.5f
#define GAMMA_W 0.5f
#define EPS_W   0.1f
#define LN_EPS_W 1e-5f

typedef unsigned short u16;
typedef unsigned int   u32;

// fp16 storage <-> fp32 compute
__device__ __forceinline__ float h2f(u16 v) {
    __half h;
    *reinterpret_cast<u16*>(&h) = v;
    return __half2float(h);
}
__device__ __forceinline__ u16 f2h(float f) {
    __half h = __float2half_rn(f);
    return *reinterpret_cast<u16*>(&h);
}
__device__ __forceinline__ int clampN(int v) {
    return (v < 0) ? 0 : ((v >= N_NODES) ? N_NODES - 1 : v);
}

// ---------------- fallback sentinel (fp32 output) ----------------
__global__ __launch_bounds__(256) void sentinel_kernel(float* out, int n) {
    int i = blockIdx.x * blockDim.x + threadIdx.x;
    if (i < n) out[i] = 2.0f;
}

// ---------------- CSR build ----------------
__global__ __launch_bounds__(256) void zero_kernel(int* p, int n) {
    int i = blockIdx.x * blockDim.x + threadIdx.x;
    if (i < n) p[i] = 0;
}

__global__ __launch_bounds__(256) void hist_kernel(const int* __restrict__ dst, int* __restrict__ deg, int e) {
    int i = blockIdx.x * blockDim.x + threadIdx.x;
    if (i < e) atomicAdd(&deg[clampN(dst[i])], 1);
}

__global__ __launch_bounds__(1024) void scan_kernel(const int* __restrict__ deg, int* __restrict__ row_ptr, int n) {
    __shared__ int sdata[1024];
    __shared__ int carry;
    int t = threadIdx.x;
    if (t == 0) carry = 0;
    for (int base = 0; base < n; base += 1024) {
        int i = base + t;
        int v = (i < n) ? deg[i] : 0;
        __syncthreads();
        sdata[t] = v;
        __syncthreads();
        for (int off = 1; off < 1024; off <<= 1) {
            int a = (t >= off) ? sdata[t - off] : 0;
            __syncthreads();
            sdata[t] += a;
            __syncthreads();
        }
        int incl = sdata[t];
        int c = carry;
        if (i < n) row_ptr[i] = c + incl - v;   // exclusive
        int total = sdata[1023];
        __syncthreads();
        if (t == 0) carry = c + total;
    }
    __syncthreads();
    if (t == 0) row_ptr[n] = carry;
}

__global__ __launch_bounds__(256) void scatter_kernel(const int* __restrict__ src, const int* __restrict__ dst,
                                                      const int* __restrict__ row_ptr, int* __restrict__ deg,
                                                      int* __restrict__ srcS, int e) {
    int i = blockIdx.x * blockDim.x + threadIdx.x;
    if (i < e) {
        int d = clampN(dst[i]);
        int old = atomicSub(&deg[d], 1);
        int pos = row_ptr[d] + old - 1;
        if (pos >= 0 && pos < e) srcS[pos] = clampN(src[i]);
    }
}

// ---------------- init GEMM (tiled): x0 = X @ W^T + b  (fp32 in, fp16 out) ----------------
// 64 nodes x 64 h per block, 256 threads (16x16), 4x4 micro-tile, k-chunk 32
__global__ __launch_bounds__(256) void init_gemm(const float* __restrict__ X,
                                                 const float* __restrict__ W,
                                                 const float* __restrict__ bias,
                                                 u16* __restrict__ out, int n_nodes) {
    __shared__ __align__(16) float xT[32][72];   // [k][node], padded
    __shared__ __align__(16) float wT[32][72];   // [k][h]
    int tid = threadIdx.x;
    int node0 = blockIdx.x * 64;
    int h0 = blockIdx.y * 64;
    int tx = tid & 15;     // node group
    int ty = tid >> 4;     // h group
    int lrow = tid >> 2;   // 0..63 loader row
    int lk = (tid & 3) * 8;

    float acc[4][4];
#pragma unroll
    for (int i = 0; i < 4; i++)
#pragma unroll
        for (int j = 0; j < 4; j++) acc[i][j] = 0.f;

    int nd = node0 + lrow;
    int ndc = (nd < n_nodes) ? nd : (n_nodes - 1);
    const float* xp = X + (long)ndc * D_IN_K;
    const float* wp = W + (long)(h0 + lrow) * D_IN_K;

    for (int k0 = 0; k0 < D_IN_K; k0 += 32) {
        __syncthreads();
#pragma unroll
        for (int j = 0; j < 8; j++) {
            int k = k0 + lk + j;
            float xv = (k < D_IN_K) ? xp[k] : 0.f;
            float wv = (k < D_IN_K) ? wp[k] : 0.f;
            xT[lk + j][lrow] = xv;
            wT[lk + j][lrow] = wv;
        }
        __syncthreads();
#pragma unroll
        for (int kk = 0; kk < 32; kk++) {
            float4 xv = *(const float4*)&xT[kk][tx * 4];
            float4 wv = *(const float4*)&wT[kk][ty * 4];
            float xa[4] = {xv.x, xv.y, xv.z, xv.w};
            float wa[4] = {wv.x, wv.y, wv.z, wv.w};
#pragma unroll
            for (int i = 0; i < 4; i++)
#pragma unroll
                for (int j = 0; j < 4; j++) acc[i][j] = fmaf(xa[i], wa[j], acc[i][j]);
        }
    }

#pragma unroll
    for (int i = 0; i < 4; i++) {
        int node = node0 + tx * 4 + i;
        if (node < n_nodes) {
            int h = h0 + ty * 4;
            ushort4 o;
            o.x = f2h(acc[i][0] + bias[h + 0]);
            o.y = f2h(acc[i][1] + bias[h + 1]);
            o.z = f2h(acc[i][2] + bias[h + 2]);
            o.w = f2h(acc[i][3] + bias[h + 3]);
            *(ushort4*)(out + (long)node * H_DIM + h) = o;
        }
    }
}

// ---------------- per-layer: al/ar projections ----------------
__global__ __launch_bounds__(256) void alar_kernel(const u16* __restrict__ x,
                                                   const float* __restrict__ attl,
                                                   const float* __restrict__ attr,
                                                   float* __restrict__ al, float* __restrict__ ar, int n) {
    int w = (blockIdx.x * blockDim.x + threadIdx.x) >> 6;
    int lane = threadIdx.x & 63;
    if (w >= n) return;
    int col = lane * 4;
    ushort4 xv = *(const ushort4*)(x + (long)w * H_DIM + col);
    float4 lv = *(const float4*)(attl + col);
    float4 rv = *(const float4*)(attr + col);
    float x0 = h2f(xv.x), x1 = h2f(xv.y), x2 = h2f(xv.z), x3 = h2f(xv.w);
    float pl = x0 * lv.x + x1 * lv.y + x2 * lv.z + x3 * lv.w;
    float pr = x0 * rv.x + x1 * rv.y + x2 * rv.z + x3 * rv.w;
#pragma unroll
    for (int off = 32; off >= 1; off >>= 1) {
        pl += __shfl_xor(pl, off);
        pr += __shfl_xor(pr, off);
    }
    if (lane == 0) { al[w] = pl; ar[w] = pr; }
}

// ---------------- per-layer: gather (parallel tanh + broadcast) + relu/LN ----------------
__global__ __launch_bounds__(256) void layer_kernel(const u16* __restrict__ xin,
                                                    const u16* __restrict__ x0,
                                                    const float* __restrict__ al,
                                                    const float* __restrict__ ar,
                                                    const int* __restrict__ row_ptr,
                                                    const int* __restrict__ srcS,
                                                    const float* __restrict__ g,
                                                    const float* __restrict__ b,
                                                    u16* __restrict__ xout, int n, int do_ln) {
    int w = (blockIdx.x * blockDim.x + threadIdx.x) >> 6;
    int lane = threadIdx.x & 63;
    if (w >= n) return;
    int col = lane * 4;

    float arn = ar[w];
    float aself = ALPHA_W * tanhf(al[w] + arn);

    ushort4 xs = *(const ushort4*)(xin + (long)w * H_DIM + col);
    float a0 = aself * h2f(xs.x);
    float a1 = aself * h2f(xs.y);
    float a2 = aself * h2f(xs.z);
    float a3 = aself * h2f(xs.w);

    ushort4 x0v = *(const ushort4*)(x0 + (long)w * H_DIM + col);
    a0 += EPS_W * h2f(x0v.x);
    a1 += EPS_W * h2f(x0v.y);
    a2 += EPS_W * h2f(x0v.z);
    a3 += EPS_W * h2f(x0v.w);

    int e0 = row_ptr[w], e1 = row_ptr[w + 1];
    for (int base = e0; base < e1; base += 64) {
        int cnt = e1 - base; if (cnt > 64) cnt = 64;
        int s = 0; float a = 0.f;
        if (lane < cnt) {
            s = clampN(srcS[base + lane]);
            a = GAMMA_W * tanhf(al[s] + arn);
        }
        for (int j = 0; j < cnt; j++) {
            int sj = __shfl(s, j);
            float aj = __shfl(a, j);
            ushort4 xv = *(const ushort4*)(xin + (long)sj * H_DIM + col);
            a0 = fmaf(aj, h2f(xv.x), a0);
            a1 = fmaf(aj, h2f(xv.y), a1);
            a2 = fmaf(aj, h2f(xv.z), a2);
            a3 = fmaf(aj, h2f(xv.w), a3);
        }
    }

    ushort4 o;
    if (do_ln) {
        float v0 = fmaxf(a0, 0.f), v1 = fmaxf(a1, 0.f), v2 = fmaxf(a2, 0.f), v3 = fmaxf(a3, 0.f);
        float sum = v0 + v1 + v2 + v3;
        float sq = v0 * v0 + v1 * v1 + v2 * v2 + v3 * v3;
#pragma unroll
        for (int off = 32; off >= 1; off >>= 1) {
            sum += __shfl_xor(sum, off);
            sq += __shfl_xor(sq, off);
        }
        float mu = sum * (1.f / 256.f);
        float var = sq * (1.f / 256.f) - mu * mu;
        var = fmaxf(var, 0.f);
        float rstd = rsqrtf(var + LN_EPS_W);
        float4 g4 = *(const float4*)(g + col);
        float4 b4 = *(const float4*)(b + col);
        o.x = f2h((v0 - mu) * rstd * g4.x + b4.x);
        o.y = f2h((v1 - mu) * rstd * g4.y + b4.y);
        o.z = f2h((v2 - mu) * rstd * g4.z + b4.z);
        o.w = f2h((v3 - mu) * rstd * g4.w + b4.w);
    } else {
        o.x = f2h(a0); o.y = f2h(a1); o.z = f2h(a2); o.w = f2h(a3);
    }
    *(ushort4*)(xout + (long)w * H_DIM + col) = o;
}

// ---------------- final: emb = x @ W_last^T + b_last ; log_softmax (fp32 OUT) ----------------
__global__ __launch_bounds__(256) void final_kernel(const u16* __restrict__ x,
                                                    const float* __restrict__ Wl,
                                                    const float* __restrict__ bl,
                                                    float* __restrict__ out, int n) {
    __shared__ float Ws[N_CLS * H_DIM];
    for (int i = threadIdx.x; i < N_CLS * H_DIM; i += blockDim.x) Ws[i] = Wl[i];
    __syncthreads();

    int w = (blockIdx.x * blockDim.x + threadIdx.x) >> 6;
    int lane = threadIdx.x & 63;
    if (w >= n) return;
    int col = lane * 4;
    ushort4 xv = *(const ushort4*)(x + (long)w * H_DIM + col);
    float x0 = h2f(xv.x), x1 = h2f(xv.y), x2 = h2f(xv.z), x3 = h2f(xv.w);

    float p[N_CLS];
#pragma unroll
    for (int c = 0; c < N_CLS; c++) {
        const float* wr = &Ws[c * H_DIM + col];
        p[c] = x0 * wr[0] + x1 * wr[1] + x2 * wr[2] + x3 * wr[3];
    }
#pragma unroll
    for (int off = 32; off >= 1; off >>= 1) {
#pragma unroll
        for (int c = 0; c < N_CLS; c++) p[c] += __shfl_xor(p[c], off);
    }
    if (lane == 0) {
        float e[N_CLS];
        float m = -1e30f;
#pragma unroll
        for (int c = 0; c < N_CLS; c++) {
            e[c] = p[c] + bl[c];
            m = fmaxf(m, e[c]);
        }
        float s = 0.f;
#pragma unroll
        for (int c = 0; c < N_CLS; c++) s += expf(e[c] - m);
        float lse = logf(s);
#pragma unroll
        for (int c = 0; c < N_CLS; c++) {
            out[(long)w * N_CLS + c] = e[c];
            out[(long)N_NODES * N_CLS + (long)w * N_CLS + c] = e[c] - m - lse;
        }
    }
}

extern "C" void kernel_launch(void* const* d_in, const int* in_sizes, int n_in,
                              void* d_out, int out_size, void* d_ws, size_t ws_size,
                              hipStream_t stream) {
    const float* x_in   = (const float*)d_in[0];
    const int*   ei     = (const int*)d_in[1];     // [2][E] planar int32
    const float* W_init = (const float*)d_in[2];
    const float* b_init = (const float*)d_in[3];
    const float* att_l  = (const float*)d_in[4];
    const float* att_r  = (const float*)d_in[5];
    const float* ln_g   = (const float*)d_in[6];
    const float* ln_b   = (const float*)d_in[7];
    const float* W_last = (const float*)d_in[8];
    const float* b_last = (const float*)d_in[9];
    float* out = (float*)d_out;                    // fp32 output

    // workspace layout (80,800,064 B total); x buffers fp16
    const size_t OFF_X0  = 0;                  // 25,600,000
    const size_t OFF_XA  = 25600000;           // 25,600,000
    const size_t OFF_XB  = 51200000;           // 25,600,000
    const size_t OFF_AL  = 76800000;           //    200,000
    const size_t OFF_AR  = 77000000;           //    200,000
    const size_t OFF_DEG = 77200000;           //    200,000
    const size_t OFF_RP  = 77400000;           //    200,064
    const size_t OFF_SRC = 77600064;           //  3,200,000
    const size_t WS_NEED = 80800064;

    if (ws_size < WS_NEED) {
        sentinel_kernel<<<(out_size + 255) / 256, 256, 0, stream>>>(out, out_size);
        return;
    }

    char* ws = (char*)d_ws;
    u16* x0  = (u16*)(ws + OFF_X0);
    u16* xA  = (u16*)(ws + OFF_XA);
    u16* xB  = (u16*)(ws + OFF_XB);
    float* al = (float*)(ws + OFF_AL);
    float* ar = (float*)(ws + OFF_AR);
    int* deg     = (int*)(ws + OFF_DEG);
    int* row_ptr = (int*)(ws + OFF_RP);
    int* srcS    = (int*)(ws + OFF_SRC);

    const int* e_src = ei;
    const int* e_dst = ei + N_EDGES;

    // --- CSR build (by dst) ---
    int zb = (N_NODES + 255) / 256;
    zero_kernel<<<zb, 256, 0, stream>>>(deg, N_NODES);
    int eb = (N_EDGES + 255) / 256;
    hist_kernel<<<eb, 256, 0, stream>>>(e_dst, deg, N_EDGES);
    scan_kernel<<<1, 1024, 0, stream>>>(deg, row_ptr, N_NODES);
    scatter_kernel<<<eb, 256, 0, stream>>>(e_src, e_dst, row_ptr, deg, srcS, N_EDGES);

    // --- init linear (tiled) ---
    dim3 gg((N_NODES + 63) / 64, H_DIM / 64);
    init_gemm<<<gg, 256, 0, stream>>>(x_in, W_init, b_init, x0, N_NODES);

    // --- layers ---
    int nb = (N_NODES * 64 + 255) / 256;   // one wave per node
    const u16* bufs_in[4]  = {x0, xA, xB, xA};
    u16* bufs_out[4]       = {xA, xB, xA, xB};
    for (int i = 0; i < 4; i++) {
        const u16* xin = bufs_in[i];
        u16* xout = bufs_out[i];
        alar_kernel<<<nb, 256, 0, stream>>>(xin, att_l + i * H_DIM, att_r + i * H_DIM, al, ar, N_NODES);
        layer_kernel<<<nb, 256, 0, stream>>>(xin, x0, al, ar, row_ptr, srcS,
                                             ln_g + i * H_DIM, ln_b + i * H_DIM,
                                             xout, N_NODES, (i < 3) ? 1 : 0);
    }

    // --- final linear + log_softmax ---
    final_kernel<<<nb, 256, 0, stream>>>(xB, W_last, b_last, out, N_NODES);
}

// Round 10
// 841.503 us; speedup vs baseline: 3.2106x; 1.2285x over previous
//
#include <hip/hip_runtime.h>
#include <hip/hip_fp16.h>

#define N_NODES 50000
#define N_EDGES 800000
#define D_IN_K  500
#define K_PAD   512
#define H_DIM   256
#define N_CLS   7
#define ALPHA_W 0.5f
#define GAMMA_W 0.5f
#define EPS_W   0.1f
#define LN_EPS_W 1e-5f

typedef unsigned short u16;
typedef unsigned int   u32;
typedef _Float16 f16;
typedef __attribute__((ext_vector_type(8))) _Float16 f16x8;
typedef __attribute__((ext_vector_type(4))) float    f32x4;

// fp16 storage <-> fp32 compute
__device__ __forceinline__ float h2f(u16 v) {
    __half h;
    *reinterpret_cast<u16*>(&h) = v;
    return __half2float(h);
}
__device__ __forceinline__ u16 f2h(float f) {
    __half h = __float2half_rn(f);
    return *reinterpret_cast<u16*>(&h);
}
__device__ __forceinline__ int clampN(int v) {
    return (v < 0) ? 0 : ((v >= N_NODES) ? N_NODES - 1 : v);
}

// ---------------- fallback sentinel (fp32 output) ----------------
__global__ __launch_bounds__(256) void sentinel_kernel(float* out, int n) {
    int i = blockIdx.x * blockDim.x + threadIdx.x;
    if (i < n) out[i] = 2.0f;
}

// ---------------- CSR build ----------------
__global__ __launch_bounds__(256) void zero_kernel(int* p, int n) {
    int i = blockIdx.x * blockDim.x + threadIdx.x;
    if (i < n) p[i] = 0;
}

__global__ __launch_bounds__(256) void hist_kernel(const int* __restrict__ dst, int* __restrict__ deg, int e) {
    int i = blockIdx.x * blockDim.x + threadIdx.x;
    if (i < e) atomicAdd(&deg[clampN(dst[i])], 1);
}

__global__ __launch_bounds__(1024) void scan_kernel(const int* __restrict__ deg, int* __restrict__ row_ptr, int n) {
    __shared__ int sdata[1024];
    __shared__ int carry;
    int t = threadIdx.x;
    if (t == 0) carry = 0;
    for (int base = 0; base < n; base += 1024) {
        int i = base + t;
        int v = (i < n) ? deg[i] : 0;
        __syncthreads();
        sdata[t] = v;
        __syncthreads();
        for (int off = 1; off < 1024; off <<= 1) {
            int a = (t >= off) ? sdata[t - off] : 0;
            __syncthreads();
            sdata[t] += a;
            __syncthreads();
        }
        int incl = sdata[t];
        int c = carry;
        if (i < n) row_ptr[i] = c + incl - v;   // exclusive
        int total = sdata[1023];
        __syncthreads();
        if (t == 0) carry = c + total;
    }
    __syncthreads();
    if (t == 0) row_ptr[n] = carry;
}

__global__ __launch_bounds__(256) void scatter_kernel(const int* __restrict__ src, const int* __restrict__ dst,
                                                      const int* __restrict__ row_ptr, int* __restrict__ deg,
                                                      int* __restrict__ srcS, int e) {
    int i = blockIdx.x * blockDim.x + threadIdx.x;
    if (i < e) {
        int d = clampN(dst[i]);
        int old = atomicSub(&deg[d], 1);
        int pos = row_ptr[d] + old - 1;
        if (pos >= 0 && pos < e) srcS[pos] = clampN(src[i]);
    }
}

// ---------------- fp32 -> fp16 conversions (k-padded to 512) ----------------
__global__ __launch_bounds__(256) void convert_x(const float* __restrict__ X, f16* __restrict__ X16) {
    long i = (long)blockIdx.x * 256 + threadIdx.x;   // over N_NODES*K_PAD
    int n = (int)(i >> 9), k = (int)(i & (K_PAD - 1));
    X16[i] = (k < D_IN_K) ? (f16)X[(long)n * D_IN_K + k] : (f16)0.f;
}

__global__ __launch_bounds__(256) void convert_w(const float* __restrict__ W, f16* __restrict__ W16) {
    int i = blockIdx.x * 256 + threadIdx.x;          // over H_DIM*K_PAD
    int n = i >> 9, k = i & (K_PAD - 1);
    W16[i] = (k < D_IN_K) ? (f16)W[n * D_IN_K + k] : (f16)0.f;
}

// ---------------- init GEMM via MFMA: x0 = X @ W^T + b  (f16 in, fp32 acc, fp16 out) ----------------
// one wave per 16 nodes x full 256 h; no LDS, no barriers.
// A-frag: X16[node0 + (lane&15)][kc*32 + (lane>>4)*8 + j]  (verified layout m120/m91)
// B-frag: W16[t*16 + (lane&15)][kc*32 + (lane>>4)*8 + j]
// C/D   : col(h%16) = lane&15, row(node%16) = (lane>>4)*4 + reg
__global__ __launch_bounds__(256) void mfma_gemm(const f16* __restrict__ X16,
                                                 const f16* __restrict__ W16,
                                                 const float* __restrict__ bias,
                                                 u16* __restrict__ out) {
    int wid  = (blockIdx.x * 256 + threadIdx.x) >> 6;
    int lane = threadIdx.x & 63;
    if (wid >= N_NODES / 16) return;
    int m    = lane & 15;
    int quad = lane >> 4;

    const f16* ap = X16 + (long)(wid * 16 + m) * K_PAD + quad * 8;
    const f16* bp = W16 + (long)m * K_PAD + quad * 8;

    f32x4 acc[16];
#pragma unroll
    for (int t = 0; t < 16; t++) acc[t] = (f32x4){0.f, 0.f, 0.f, 0.f};

    for (int kc = 0; kc < K_PAD / 32; kc++) {
        f16x8 a = *(const f16x8*)(ap + kc * 32);
#pragma unroll
        for (int t = 0; t < 16; t++) {
            f16x8 b = *(const f16x8*)(bp + (long)t * 16 * K_PAD + kc * 32);
            acc[t] = __builtin_amdgcn_mfma_f32_16x16x32_f16(a, b, acc[t], 0, 0, 0);
        }
    }

    int nodebase = wid * 16 + quad * 4;
#pragma unroll
    for (int t = 0; t < 16; t++) {
        int h = t * 16 + m;
        float bv = bias[h];
#pragma unroll
        for (int r = 0; r < 4; r++) {
            out[(long)(nodebase + r) * H_DIM + h] = f2h(acc[t][r] + bv);
        }
    }
}

// ---------------- per-layer: al/ar projections ----------------
__global__ __launch_bounds__(256) void alar_kernel(const u16* __restrict__ x,
                                                   const float* __restrict__ attl,
                                                   const float* __restrict__ attr,
                                                   float* __restrict__ al, float* __restrict__ ar, int n) {
    int w = (blockIdx.x * blockDim.x + threadIdx.x) >> 6;
    int lane = threadIdx.x & 63;
    if (w >= n) return;
    int col = lane * 4;
    ushort4 xv = *(const ushort4*)(x + (long)w * H_DIM + col);
    float4 lv = *(const float4*)(attl + col);
    float4 rv = *(const float4*)(attr + col);
    float x0 = h2f(xv.x), x1 = h2f(xv.y), x2 = h2f(xv.z), x3 = h2f(xv.w);
    float pl = x0 * lv.x + x1 * lv.y + x2 * lv.z + x3 * lv.w;
    float pr = x0 * rv.x + x1 * rv.y + x2 * rv.z + x3 * rv.w;
#pragma unroll
    for (int off = 32; off >= 1; off >>= 1) {
        pl += __shfl_xor(pl, off);
        pr += __shfl_xor(pr, off);
    }
    if (lane == 0) { al[w] = pl; ar[w] = pr; }
}

// ---------------- per-layer: gather (parallel tanh + broadcast) + relu/LN ----------------
__global__ __launch_bounds__(256) void layer_kernel(const u16* __restrict__ xin,
                                                    const u16* __restrict__ x0,
                                                    const float* __restrict__ al,
                                                    const float* __restrict__ ar,
                                                    const int* __restrict__ row_ptr,
                                                    const int* __restrict__ srcS,
                                                    const float* __restrict__ g,
                                                    const float* __restrict__ b,
                                                    u16* __restrict__ xout, int n, int do_ln) {
    int w = (blockIdx.x * blockDim.x + threadIdx.x) >> 6;
    int lane = threadIdx.x & 63;
    if (w >= n) return;
    int col = lane * 4;

    float arn = ar[w];
    float aself = ALPHA_W * tanhf(al[w] + arn);

    ushort4 xs = *(const ushort4*)(xin + (long)w * H_DIM + col);
    float a0 = aself * h2f(xs.x);
    float a1 = aself * h2f(xs.y);
    float a2 = aself * h2f(xs.z);
    float a3 = aself * h2f(xs.w);

    ushort4 x0v = *(const ushort4*)(x0 + (long)w * H_DIM + col);
    a0 += EPS_W * h2f(x0v.x);
    a1 += EPS_W * h2f(x0v.y);
    a2 += EPS_W * h2f(x0v.z);
    a3 += EPS_W * h2f(x0v.w);

    int e0 = row_ptr[w], e1 = row_ptr[w + 1];
    for (int base = e0; base < e1; base += 64) {
        int cnt = e1 - base; if (cnt > 64) cnt = 64;
        int s = 0; float a = 0.f;
        if (lane < cnt) {
            s = clampN(srcS[base + lane]);
            a = GAMMA_W * tanhf(al[s] + arn);
        }
        for (int j = 0; j < cnt; j++) {
            int sj = __shfl(s, j);
            float aj = __shfl(a, j);
            ushort4 xv = *(const ushort4*)(xin + (long)sj * H_DIM + col);
            a0 = fmaf(aj, h2f(xv.x), a0);
            a1 = fmaf(aj, h2f(xv.y), a1);
            a2 = fmaf(aj, h2f(xv.z), a2);
            a3 = fmaf(aj, h2f(xv.w), a3);
        }
    }

    ushort4 o;
    if (do_ln) {
        float v0 = fmaxf(a0, 0.f), v1 = fmaxf(a1, 0.f), v2 = fmaxf(a2, 0.f), v3 = fmaxf(a3, 0.f);
        float sum = v0 + v1 + v2 + v3;
        float sq = v0 * v0 + v1 * v1 + v2 * v2 + v3 * v3;
#pragma unroll
        for (int off = 32; off >= 1; off >>= 1) {
            sum += __shfl_xor(sum, off);
            sq += __shfl_xor(sq, off);
        }
        float mu = sum * (1.f / 256.f);
        float var = sq * (1.f / 256.f) - mu * mu;
        var = fmaxf(var, 0.f);
        float rstd = rsqrtf(var + LN_EPS_W);
        float4 g4 = *(const float4*)(g + col);
        float4 b4 = *(const float4*)(b + col);
        o.x = f2h((v0 - mu) * rstd * g4.x + b4.x);
        o.y = f2h((v1 - mu) * rstd * g4.y + b4.y);
        o.z = f2h((v2 - mu) * rstd * g4.z + b4.z);
        o.w = f2h((v3 - mu) * rstd * g4.w + b4.w);
    } else {
        o.x = f2h(a0); o.y = f2h(a1); o.z = f2h(a2); o.w = f2h(a3);
    }
    *(ushort4*)(xout + (long)w * H_DIM + col) = o;
}

// ---------------- final: emb = x @ W_last^T + b_last ; log_softmax (fp32 OUT) ----------------
__global__ __launch_bounds__(256) void final_kernel(const u16* __restrict__ x,
                                                    const float* __restrict__ Wl,
                                                    const float* __restrict__ bl,
                                                    float* __restrict__ out, int n) {
    __shared__ float Ws[N_CLS * H_DIM];
    for (int i = threadIdx.x; i < N_CLS * H_DIM; i += blockDim.x) Ws[i] = Wl[i];
    __syncthreads();

    int w = (blockIdx.x * blockDim.x + threadIdx.x) >> 6;
    int lane = threadIdx.x & 63;
    if (w >= n) return;
    int col = lane * 4;
    ushort4 xv = *(const ushort4*)(x + (long)w * H_DIM + col);
    float x0 = h2f(xv.x), x1 = h2f(xv.y), x2 = h2f(xv.z), x3 = h2f(xv.w);

    float p[N_CLS];
#pragma unroll
    for (int c = 0; c < N_CLS; c++) {
        const float* wr = &Ws[c * H_DIM + col];
        p[c] = x0 * wr[0] + x1 * wr[1] + x2 * wr[2] + x3 * wr[3];
    }
#pragma unroll
    for (int off = 32; off >= 1; off >>= 1) {
#pragma unroll
        for (int c = 0; c < N_CLS; c++) p[c] += __shfl_xor(p[c], off);
    }
    if (lane == 0) {
        float e[N_CLS];
        float m = -1e30f;
#pragma unroll
        for (int c = 0; c < N_CLS; c++) {
            e[c] = p[c] + bl[c];
            m = fmaxf(m, e[c]);
        }
        float s = 0.f;
#pragma unroll
        for (int c = 0; c < N_CLS; c++) s += expf(e[c] - m);
        float lse = logf(s);
#pragma unroll
        for (int c = 0; c < N_CLS; c++) {
            out[(long)w * N_CLS + c] = e[c];
            out[(long)N_NODES * N_CLS + (long)w * N_CLS + c] = e[c] - m - lse;
        }
    }
}

extern "C" void kernel_launch(void* const* d_in, const int* in_sizes, int n_in,
                              void* d_out, int out_size, void* d_ws, size_t ws_size,
                              hipStream_t stream) {
    const float* x_in   = (const float*)d_in[0];
    const int*   ei     = (const int*)d_in[1];     // [2][E] planar int32
    const float* W_init = (const float*)d_in[2];
    const float* b_init = (const float*)d_in[3];
    const float* att_l  = (const float*)d_in[4];
    const float* att_r  = (const float*)d_in[5];
    const float* ln_g   = (const float*)d_in[6];
    const float* ln_b   = (const float*)d_in[7];
    const float* W_last = (const float*)d_in[8];
    const float* b_last = (const float*)d_in[9];
    float* out = (float*)d_out;                    // fp32 output

    // workspace layout (80,800,064 B total)
    // During init: X16 (fp16 50000x512 = 51.2MB) occupies xA+xB; W16 occupies al/ar.
    // Layers reclaim xA/xB/al/ar afterwards (stream-serialized).
    const size_t OFF_X0  = 0;                  // 25,600,000
    const size_t OFF_XA  = 25600000;           // 25,600,000
    const size_t OFF_XB  = 51200000;           // 25,600,000
    const size_t OFF_AL  = 76800000;           //    200,000
    const size_t OFF_AR  = 77000000;           //    200,000
    const size_t OFF_DEG = 77200000;           //    200,000
    const size_t OFF_RP  = 77400000;           //    200,064
    const size_t OFF_SRC = 77600064;           //  3,200,000
    const size_t WS_NEED = 80800064;

    if (ws_size < WS_NEED) {
        sentinel_kernel<<<(out_size + 255) / 256, 256, 0, stream>>>(out, out_size);
        return;
    }

    char* ws = (char*)d_ws;
    u16* x0  = (u16*)(ws + OFF_X0);
    u16* xA  = (u16*)(ws + OFF_XA);
    u16* xB  = (u16*)(ws + OFF_XB);
    f16* X16 = (f16*)(ws + OFF_XA);            // 51.2 MB spanning xA+xB (init only)
    f16* W16 = (f16*)(ws + OFF_AL);            // 262,144 B in al/ar region (init only)
    float* al = (float*)(ws + OFF_AL);
    float* ar = (float*)(ws + OFF_AR);
    int* deg     = (int*)(ws + OFF_DEG);
    int* row_ptr = (int*)(ws + OFF_RP);
    int* srcS    = (int*)(ws + OFF_SRC);

    const int* e_src = ei;
    const int* e_dst = ei + N_EDGES;

    // --- CSR build (by dst) ---
    int zb = (N_NODES + 255) / 256;
    zero_kernel<<<zb, 256, 0, stream>>>(deg, N_NODES);
    int eb = (N_EDGES + 255) / 256;
    hist_kernel<<<eb, 256, 0, stream>>>(e_dst, deg, N_EDGES);
    scan_kernel<<<1, 1024, 0, stream>>>(deg, row_ptr, N_NODES);
    scatter_kernel<<<eb, 256, 0, stream>>>(e_src, e_dst, row_ptr, deg, srcS, N_EDGES);

    // --- init linear: convert to fp16, then MFMA GEMM ---
    convert_x<<<(N_NODES * K_PAD) / 256, 256, 0, stream>>>(x_in, X16);
    convert_w<<<(H_DIM * K_PAD) / 256, 256, 0, stream>>>(W_init, W16);
    mfma_gemm<<<(N_NODES / 16 + 3) / 4, 256, 0, stream>>>(X16, W16, b_init, x0);

    // --- layers ---
    int nb = (N_NODES * 64 + 255) / 256;   // one wave per node
    const u16* bufs_in[4]  = {x0, xA, xB, xA};
    u16* bufs_out[4]       = {xA, xB, xA, xB};
    for (int i = 0; i < 4; i++) {
        const u16* xin = bufs_in[i];
        u16* xout = bufs_out[i];
        alar_kernel<<<nb, 256, 0, stream>>>(xin, att_l + i * H_DIM, att_r + i * H_DIM, al, ar, N_NODES);
        layer_kernel<<<nb, 256, 0, stream>>>(xin, x0, al, ar, row_ptr, srcS,
                                             ln_g + i * H_DIM, ln_b + i * H_DIM,
                                             xout, N_NODES, (i < 3) ? 1 : 0);
    }

    // --- final linear + log_softmax ---
    final_kernel<<<nb, 256, 0, stream>>>(xB, W_last, b_last, out, N_NODES);
}

// Round 11
// 728.445 us; speedup vs baseline: 3.7089x; 1.1552x over previous
//
#include <hip/hip_runtime.h>
#include <hip/hip_fp16.h>

#define N_NODES 50000
#define N_EDGES 800000
#define D_IN_K  500
#define K_PAD   512
#define H_DIM   256
#define N_CLS   7
#define ALPHA_W 0.5f
#define GAMMA_W 0.5f
#define EPS_W   0.1f
#define LN_EPS_W 1e-5f

typedef unsigned short u16;
typedef unsigned int   u32;
typedef _Float16 f16;
typedef __attribute__((ext_vector_type(8))) _Float16 f16x8;
typedef __attribute__((ext_vector_type(4))) float    f32x4;
typedef __attribute__((ext_vector_type(8))) unsigned short u16x8;

__device__ __forceinline__ float h2f(u16 v) {
    __half h;
    *reinterpret_cast<u16*>(&h) = v;
    return __half2float(h);
}
__device__ __forceinline__ u16 f2h(float f) {
    __half h = __float2half_rn(f);
    return *reinterpret_cast<u16*>(&h);
}
__device__ __forceinline__ int clampN(int v) {
    return (v < 0) ? 0 : ((v >= N_NODES) ? N_NODES - 1 : v);
}

// ---------------- fallback sentinel (fp32 output) ----------------
__global__ __launch_bounds__(256) void sentinel_kernel(float* out, int n) {
    int i = blockIdx.x * blockDim.x + threadIdx.x;
    if (i < n) out[i] = 2.0f;
}

// ---------------- CSR build ----------------
__global__ __launch_bounds__(256) void zero_kernel(int* p, int n) {
    int i = blockIdx.x * blockDim.x + threadIdx.x;
    if (i < n) p[i] = 0;
}

__global__ __launch_bounds__(256) void hist_kernel(const int* __restrict__ dst, int* __restrict__ deg, int e) {
    int i = blockIdx.x * blockDim.x + threadIdx.x;
    if (i < e) atomicAdd(&deg[clampN(dst[i])], 1);
}

__global__ __launch_bounds__(1024) void scan_kernel(const int* __restrict__ deg, int* __restrict__ row_ptr, int n) {
    __shared__ int sdata[1024];
    __shared__ int carry;
    int t = threadIdx.x;
    if (t == 0) carry = 0;
    for (int base = 0; base < n; base += 1024) {
        int i = base + t;
        int v = (i < n) ? deg[i] : 0;
        __syncthreads();
        sdata[t] = v;
        __syncthreads();
        for (int off = 1; off < 1024; off <<= 1) {
            int a = (t >= off) ? sdata[t - off] : 0;
            __syncthreads();
            sdata[t] += a;
            __syncthreads();
        }
        int incl = sdata[t];
        int c = carry;
        if (i < n) row_ptr[i] = c + incl - v;   // exclusive
        int total = sdata[1023];
        __syncthreads();
        if (t == 0) carry = c + total;
    }
    __syncthreads();
    if (t == 0) row_ptr[n] = carry;
}

__global__ __launch_bounds__(256) void scatter_kernel(const int* __restrict__ src, const int* __restrict__ dst,
                                                      const int* __restrict__ row_ptr, int* __restrict__ deg,
                                                      int* __restrict__ srcS, int e) {
    int i = blockIdx.x * blockDim.x + threadIdx.x;
    if (i < e) {
        int d = clampN(dst[i]);
        int old = atomicSub(&deg[d], 1);
        int pos = row_ptr[d] + old - 1;
        if (pos >= 0 && pos < e) srcS[pos] = clampN(src[i]);
    }
}

// ---------------- fp32 -> fp16 conversions (k-padded to 512) ----------------
__global__ __launch_bounds__(256) void convert_x(const float* __restrict__ X, f16* __restrict__ X16) {
    long i = (long)blockIdx.x * 256 + threadIdx.x;   // over N_NODES*K_PAD
    int n = (int)(i >> 9), k = (int)(i & (K_PAD - 1));
    X16[i] = (k < D_IN_K) ? (f16)X[(long)n * D_IN_K + k] : (f16)0.f;
}

__global__ __launch_bounds__(256) void convert_w(const float* __restrict__ W, f16* __restrict__ W16) {
    int i = blockIdx.x * 256 + threadIdx.x;          // over H_DIM*K_PAD
    int n = i >> 9, k = i & (K_PAD - 1);
    W16[i] = (k < D_IN_K) ? (f16)W[n * D_IN_K + k] : (f16)0.f;
}

// ---------------- init GEMM via MFMA, LDS-staged W ----------------
// block = 256 thr = 4 waves = 64 nodes x 256 h; A-frags held in VGPRs (loaded once);
// W staged in LDS in 4 phases of 64 h; stride 520 f16 -> 2-way bank conflicts only.
#define W_STRIDE 520
__global__ __launch_bounds__(256) void mfma_gemm2(const f16* __restrict__ X16,
                                                  const f16* __restrict__ W16,
                                                  const float* __restrict__ bias,
                                                  u16* __restrict__ out) {
    __shared__ __align__(16) f16 wlds[64 * W_STRIDE];
    int tid  = threadIdx.x;
    int wl   = tid >> 6;
    int lane = tid & 63;
    int m    = lane & 15;
    int quad = lane >> 4;

    int node = blockIdx.x * 64 + wl * 16 + m;
    int nodec = (node < N_NODES) ? node : N_NODES - 1;

    // load all A-fragments once (16 KB/wave)
    f16x8 a[16];
    const f16* ap = X16 + (long)nodec * K_PAD + quad * 8;
#pragma unroll
    for (int kc = 0; kc < 16; kc++) a[kc] = *(const f16x8*)(ap + kc * 32);

    for (int p = 0; p < 4; p++) {
        __syncthreads();
        // stage W rows p*64 .. p*64+63 (64 x 512 f16 = 64 KB)
        for (int idx = tid; idx < 64 * 64; idx += 256) {
            int row = idx >> 6, c = idx & 63;
            *(f16x8*)&wlds[row * W_STRIDE + c * 8] = *(const f16x8*)&W16[(p * 64 + row) * K_PAD + c * 8];
        }
        __syncthreads();

        f32x4 acc[4];
#pragma unroll
        for (int t = 0; t < 4; t++) acc[t] = (f32x4){0.f, 0.f, 0.f, 0.f};

        for (int kc = 0; kc < 16; kc++) {
#pragma unroll
            for (int t = 0; t < 4; t++) {
                f16x8 b = *(const f16x8*)&wlds[(t * 16 + m) * W_STRIDE + kc * 32 + quad * 8];
                acc[t] = __builtin_amdgcn_mfma_f32_16x16x32_f16(a[kc], b, acc[t], 0, 0, 0);
            }
        }

        int nb = blockIdx.x * 64 + wl * 16 + quad * 4;
#pragma unroll
        for (int t = 0; t < 4; t++) {
            int h = p * 64 + t * 16 + m;
            float bv = bias[h];
#pragma unroll
            for (int r = 0; r < 4; r++) {
                int nrow = nb + r;
                if (nrow < N_NODES) out[(long)nrow * H_DIM + h] = f2h(acc[t][r] + bv);
            }
        }
    }
}

// ---------------- al/ar for layer 0 (from x0) ----------------
__global__ __launch_bounds__(256) void alar_kernel(const u16* __restrict__ x,
                                                   const float* __restrict__ attl,
                                                   const float* __restrict__ attr,
                                                   float* __restrict__ al, float* __restrict__ ar, int n) {
    int w = (blockIdx.x * blockDim.x + threadIdx.x) >> 6;
    int lane = threadIdx.x & 63;
    if (w >= n) return;
    int col = lane * 4;
    ushort4 xv = *(const ushort4*)(x + (long)w * H_DIM + col);
    float4 lv = *(const float4*)(attl + col);
    float4 rv = *(const float4*)(attr + col);
    float x0 = h2f(xv.x), x1 = h2f(xv.y), x2 = h2f(xv.z), x3 = h2f(xv.w);
    float pl = x0 * lv.x + x1 * lv.y + x2 * lv.z + x3 * lv.w;
    float pr = x0 * rv.x + x1 * rv.y + x2 * rv.z + x3 * rv.w;
#pragma unroll
    for (int off = 32; off >= 1; off >>= 1) {
        pl += __shfl_xor(pl, off);
        pr += __shfl_xor(pr, off);
    }
    if (lane == 0) { al[w] = pl; ar[w] = pr; }
}

// ---------------- layer v2: half-wave gather (2 edges/iter, 16B loads) + relu/LN
//                  + fused next-layer al/ar (al double-buffered, ar in-place) ----------------
__global__ __launch_bounds__(256) void layer_kernel2(const u16* __restrict__ xin,
                                                     const u16* __restrict__ x0,
                                                     const float* __restrict__ alIn,
                                                     float* __restrict__ alOut,
                                                     float* __restrict__ ar,
                                                     const int* __restrict__ row_ptr,
                                                     const int* __restrict__ srcS,
                                                     const float* __restrict__ g,
                                                     const float* __restrict__ b,
                                                     const float* __restrict__ attlN,
                                                     const float* __restrict__ attrN,
                                                     u16* __restrict__ xout, int n, int do_ln) {
    int w = (blockIdx.x * blockDim.x + threadIdx.x) >> 6;
    int lane = threadIdx.x & 63;
    if (w >= n) return;
    int half = lane >> 5;
    int sub  = lane & 31;
    int col  = sub * 8;          // 8 dims per lane, dims duplicated across halves

    float arn = ar[w];
    float aself = ALPHA_W * tanhf(alIn[w] + arn);

    float acc[8];
    if (half == 0) {
        u16x8 xs  = *(const u16x8*)(xin + (long)w * H_DIM + col);
        u16x8 x0v = *(const u16x8*)(x0  + (long)w * H_DIM + col);
#pragma unroll
        for (int k = 0; k < 8; k++) acc[k] = aself * h2f(xs[k]) + EPS_W * h2f(x0v[k]);
    } else {
#pragma unroll
        for (int k = 0; k < 8; k++) acc[k] = 0.f;
    }

    int e0 = row_ptr[w], e1 = row_ptr[w + 1];
    for (int base = e0; base < e1; base += 64) {
        int cnt = e1 - base; if (cnt > 64) cnt = 64;
        int s = 0; float a = 0.f;
        if (lane < cnt) {
            s = clampN(srcS[base + lane]);
            a = GAMMA_W * tanhf(alIn[s] + arn);
        }
        for (int j = 0; j < cnt; j += 2) {
            int idx = j + half;                 // half 0: even edge, half 1: odd edge
            int sj  = __shfl(s, idx);           // lanes >= cnt hold s=0,a=0 -> safe
            float aj = __shfl(a, idx);
            u16x8 xv = *(const u16x8*)(xin + (long)sj * H_DIM + col);
#pragma unroll
            for (int k = 0; k < 8; k++) acc[k] = fmaf(aj, h2f(xv[k]), acc[k]);
        }
    }

    // combine halves (both halves end with identical full sums)
#pragma unroll
    for (int k = 0; k < 8; k++) acc[k] += __shfl(acc[k], lane ^ 32);

    u16x8 o;
    if (do_ln) {
        float v[8];
        float sum = 0.f, sq = 0.f;
#pragma unroll
        for (int k = 0; k < 8; k++) {
            v[k] = fmaxf(acc[k], 0.f);
            sum += v[k];
            sq  += v[k] * v[k];
        }
#pragma unroll
        for (int off = 16; off >= 1; off >>= 1) {   // reduce within each 32-lane half
            sum += __shfl_xor(sum, off);
            sq  += __shfl_xor(sq, off);
        }
        float mu = sum * (1.f / 256.f);
        float var = fmaxf(sq * (1.f / 256.f) - mu * mu, 0.f);
        float rstd = rsqrtf(var + LN_EPS_W);
        float4 ga = *(const float4*)(g + col);
        float4 gb = *(const float4*)(g + col + 4);
        float4 ba = *(const float4*)(b + col);
        float4 bb = *(const float4*)(b + col + 4);
        float gg[8] = {ga.x, ga.y, ga.z, ga.w, gb.x, gb.y, gb.z, gb.w};
        float bbv[8] = {ba.x, ba.y, ba.z, ba.w, bb.x, bb.y, bb.z, bb.w};
        float pl = 0.f, pr = 0.f;
        float4 la = *(const float4*)(attlN + col);
        float4 lb = *(const float4*)(attlN + col + 4);
        float4 ra = *(const float4*)(attrN + col);
        float4 rb = *(const float4*)(attrN + col + 4);
        float ll[8] = {la.x, la.y, la.z, la.w, lb.x, lb.y, lb.z, lb.w};
        float rr[8] = {ra.x, ra.y, ra.z, ra.w, rb.x, rb.y, rb.z, rb.w};
#pragma unroll
        for (int k = 0; k < 8; k++) {
            float val = (v[k] - mu) * rstd * gg[k] + bbv[k];
            o[k] = f2h(val);
            pl += val * ll[k];
            pr += val * rr[k];
        }
#pragma unroll
        for (int off = 16; off >= 1; off >>= 1) {
            pl += __shfl_xor(pl, off);
            pr += __shfl_xor(pr, off);
        }
        if (lane == 0) { alOut[w] = pl; ar[w] = pr; }   // ar in-place: only own wave reads ar[w]
    } else {
#pragma unroll
        for (int k = 0; k < 8; k++) o[k] = f2h(acc[k]);
    }
    if (half == 0) *(u16x8*)(xout + (long)w * H_DIM + col) = o;
}

// ---------------- final: emb = x @ W_last^T + b_last ; log_softmax (fp32 OUT) ----------------
__global__ __launch_bounds__(256) void final_kernel(const u16* __restrict__ x,
                                                    const float* __restrict__ Wl,
                                                    const float* __restrict__ bl,
                                                    float* __restrict__ out, int n) {
    __shared__ float Ws[N_CLS * H_DIM];
    for (int i = threadIdx.x; i < N_CLS * H_DIM; i += blockDim.x) Ws[i] = Wl[i];
    __syncthreads();

    int w = (blockIdx.x * blockDim.x + threadIdx.x) >> 6;
    int lane = threadIdx.x & 63;
    if (w >= n) return;
    int col = lane * 4;
    ushort4 xv = *(const ushort4*)(x + (long)w * H_DIM + col);
    float x0 = h2f(xv.x), x1 = h2f(xv.y), x2 = h2f(xv.z), x3 = h2f(xv.w);

    float p[N_CLS];
#pragma unroll
    for (int c = 0; c < N_CLS; c++) {
        const float* wr = &Ws[c * H_DIM + col];
        p[c] = x0 * wr[0] + x1 * wr[1] + x2 * wr[2] + x3 * wr[3];
    }
#pragma unroll
    for (int off = 32; off >= 1; off >>= 1) {
#pragma unroll
        for (int c = 0; c < N_CLS; c++) p[c] += __shfl_xor(p[c], off);
    }
    if (lane == 0) {
        float e[N_CLS];
        float m = -1e30f;
#pragma unroll
        for (int c = 0; c < N_CLS; c++) {
            e[c] = p[c] + bl[c];
            m = fmaxf(m, e[c]);
        }
        float s = 0.f;
#pragma unroll
        for (int c = 0; c < N_CLS; c++) s += expf(e[c] - m);
        float lse = logf(s);
#pragma unroll
        for (int c = 0; c < N_CLS; c++) {
            out[(long)w * N_CLS + c] = e[c];
            out[(long)N_NODES * N_CLS + (long)w * N_CLS + c] = e[c] - m - lse;
        }
    }
}

extern "C" void kernel_launch(void* const* d_in, const int* in_sizes, int n_in,
                              void* d_out, int out_size, void* d_ws, size_t ws_size,
                              hipStream_t stream) {
    const float* x_in   = (const float*)d_in[0];
    const int*   ei     = (const int*)d_in[1];     // [2][E] planar int32
    const float* W_init = (const float*)d_in[2];
    const float* b_init = (const float*)d_in[3];
    const float* att_l  = (const float*)d_in[4];
    const float* att_r  = (const float*)d_in[5];
    const float* ln_g   = (const float*)d_in[6];
    const float* ln_b   = (const float*)d_in[7];
    const float* W_last = (const float*)d_in[8];
    const float* b_last = (const float*)d_in[9];
    float* out = (float*)d_out;

    // workspace layout (80,800,064 B total)
    const size_t OFF_X0  = 0;                  // 25,600,000
    const size_t OFF_XA  = 25600000;           // 25,600,000 (X16 spans XA+XB during init)
    const size_t OFF_XB  = 51200000;           // 25,600,000
    const size_t OFF_AL  = 76800000;           //    200,000 (W16 overlays AL/AR during init)
    const size_t OFF_AR  = 77000000;           //    200,000
    const size_t OFF_DEG = 77200000;           //    200,000 (al2 after CSR build)
    const size_t OFF_RP  = 77400000;           //    200,064
    const size_t OFF_SRC = 77600064;           //  3,200,000
    const size_t WS_NEED = 80800064;

    if (ws_size < WS_NEED) {
        sentinel_kernel<<<(out_size + 255) / 256, 256, 0, stream>>>(out, out_size);
        return;
    }

    char* ws = (char*)d_ws;
    u16* x0  = (u16*)(ws + OFF_X0);
    u16* xA  = (u16*)(ws + OFF_XA);
    u16* xB  = (u16*)(ws + OFF_XB);
    f16* X16 = (f16*)(ws + OFF_XA);
    f16* W16 = (f16*)(ws + OFF_AL);
    float* al  = (float*)(ws + OFF_AL);
    float* ar  = (float*)(ws + OFF_AR);
    float* al2 = (float*)(ws + OFF_DEG);       // reuse deg after CSR build
    int* deg     = (int*)(ws + OFF_DEG);
    int* row_ptr = (int*)(ws + OFF_RP);
    int* srcS    = (int*)(ws + OFF_SRC);

    const int* e_src = ei;
    const int* e_dst = ei + N_EDGES;

    // --- CSR build (by dst) ---
    int zb = (N_NODES + 255) / 256;
    zero_kernel<<<zb, 256, 0, stream>>>(deg, N_NODES);
    int eb = (N_EDGES + 255) / 256;
    hist_kernel<<<eb, 256, 0, stream>>>(e_dst, deg, N_EDGES);
    scan_kernel<<<1, 1024, 0, stream>>>(deg, row_ptr, N_NODES);
    scatter_kernel<<<eb, 256, 0, stream>>>(e_src, e_dst, row_ptr, deg, srcS, N_EDGES);

    // --- init linear: fp16 convert + LDS-staged MFMA GEMM ---
    convert_x<<<(N_NODES * K_PAD) / 256, 256, 0, stream>>>(x_in, X16);
    convert_w<<<(H_DIM * K_PAD) / 256, 256, 0, stream>>>(W_init, W16);
    mfma_gemm2<<<(N_NODES + 63) / 64, 256, 0, stream>>>(X16, W16, b_init, x0);

    // --- al/ar for layer 0 ---
    int nb = (N_NODES * 64 + 255) / 256;   // one wave per node
    alar_kernel<<<nb, 256, 0, stream>>>(x0, att_l, att_r, al, ar, N_NODES);

    // --- layers (al ping-pongs al <-> al2; ar in-place) ---
    const u16* bufs_in[4]   = {x0, xA, xB, xA};
    u16* bufs_out[4]        = {xA, xB, xA, xB};
    const float* al_in[4]   = {al, al2, al, al2};
    float* al_out[4]        = {al2, al, al2, al};   // unused for i=3
    for (int i = 0; i < 4; i++) {
        int nxt = (i < 3) ? (i + 1) : i;   // att pointers for fused next-layer al/ar (dummy for i=3)
        layer_kernel2<<<nb, 256, 0, stream>>>(bufs_in[i], x0, al_in[i], al_out[i], ar,
                                              row_ptr, srcS,
                                              ln_g + i * H_DIM, ln_b + i * H_DIM,
                                              att_l + nxt * H_DIM, att_r + nxt * H_DIM,
                                              bufs_out[i], N_NODES, (i < 3) ? 1 : 0);
    }

    // --- final linear + log_softmax ---
    final_kernel<<<nb, 256, 0, stream>>>(xB, W_last, b_last, out, N_NODES);
}

// Round 12
// 650.093 us; speedup vs baseline: 4.1559x; 1.1205x over previous
//
#include <hip/hip_runtime.h>
#include <hip/hip_fp16.h>

#define N_NODES 50000
#define N_EDGES 800000
#define D_IN_K  500
#define K_PAD   512
#define H_DIM   256
#define N_CLS   7
#define ALPHA_W 0.5f
#define GAMMA_W 0.5f
#define EPS_W   0.1f
#define LN_EPS_W 1e-5f

#define SCAN_B 256
#define SCAN_NB ((N_NODES + SCAN_B - 1) / SCAN_B)   // 196

typedef unsigned short u16;
typedef unsigned int   u32;
typedef _Float16 f16;
typedef __attribute__((ext_vector_type(8))) _Float16 f16x8;
typedef __attribute__((ext_vector_type(4))) float    f32x4;
typedef __attribute__((ext_vector_type(8))) unsigned short u16x8;

__device__ __forceinline__ float h2f(u16 v) {
    __half h;
    *reinterpret_cast<u16*>(&h) = v;
    return __half2float(h);
}
__device__ __forceinline__ u16 f2h(float f) {
    __half h = __float2half_rn(f);
    return *reinterpret_cast<u16*>(&h);
}
__device__ __forceinline__ int clampN(int v) {
    return (v < 0) ? 0 : ((v >= N_NODES) ? N_NODES - 1 : v);
}

// ---------------- fallback sentinel (fp32 output) ----------------
__global__ __launch_bounds__(256) void sentinel_kernel(float* out, int n) {
    int i = blockIdx.x * blockDim.x + threadIdx.x;
    if (i < n) out[i] = 2.0f;
}

// ---------------- CSR build ----------------
__global__ __launch_bounds__(256) void zero_kernel(int* p, int n) {
    int i = blockIdx.x * blockDim.x + threadIdx.x;
    if (i < n) p[i] = 0;
}

__global__ __launch_bounds__(256) void hist_kernel(const int* __restrict__ dst, int* __restrict__ deg, int e) {
    int i = blockIdx.x * blockDim.x + threadIdx.x;
    if (i < e) atomicAdd(&deg[clampN(dst[i])], 1);
}

// two-level scan: (a) per-block local exclusive prefix + block sums
__global__ __launch_bounds__(SCAN_B) void scan_a(const int* __restrict__ deg, int* __restrict__ row_ptr,
                                                 int* __restrict__ bsum) {
    __shared__ int sdata[SCAN_B];
    int t = threadIdx.x;
    int i = blockIdx.x * SCAN_B + t;
    int v = (i < N_NODES) ? deg[i] : 0;
    sdata[t] = v;
    __syncthreads();
#pragma unroll
    for (int off = 1; off < SCAN_B; off <<= 1) {
        int a = (t >= off) ? sdata[t - off] : 0;
        __syncthreads();
        sdata[t] += a;
        __syncthreads();
    }
    if (i < N_NODES) row_ptr[i] = sdata[t] - v;   // local exclusive
    if (t == SCAN_B - 1) bsum[blockIdx.x] = sdata[t];
}

// (b) single-block exclusive scan of block sums (SCAN_NB <= 256)
__global__ __launch_bounds__(SCAN_B) void scan_b(int* __restrict__ bsum, int* __restrict__ boff,
                                                 int* __restrict__ row_ptr) {
    __shared__ int sdata[SCAN_B];
    int t = threadIdx.x;
    int v = (t < SCAN_NB) ? bsum[t] : 0;
    sdata[t] = v;
    __syncthreads();
#pragma unroll
    for (int off = 1; off < SCAN_B; off <<= 1) {
        int a = (t >= off) ? sdata[t - off] : 0;
        __syncthreads();
        sdata[t] += a;
        __syncthreads();
    }
    if (t < SCAN_NB) boff[t] = sdata[t] - v;      // exclusive
    if (t == SCAN_B - 1) row_ptr[N_NODES] = sdata[t];   // grand total (= N_EDGES)
}

// (c) add block offsets
__global__ __launch_bounds__(SCAN_B) void scan_c(int* __restrict__ row_ptr, const int* __restrict__ boff) {
    int i = blockIdx.x * SCAN_B + threadIdx.x;
    if (i < N_NODES) row_ptr[i] += boff[blockIdx.x];
}

__global__ __launch_bounds__(256) void scatter_kernel(const int* __restrict__ src, const int* __restrict__ dst,
                                                      const int* __restrict__ row_ptr, int* __restrict__ deg,
                                                      int* __restrict__ srcS, int e) {
    int i = blockIdx.x * blockDim.x + threadIdx.x;
    if (i < e) {
        int d = clampN(dst[i]);
        int old = atomicSub(&deg[d], 1);
        int pos = row_ptr[d] + old - 1;
        if (pos >= 0 && pos < e) srcS[pos] = clampN(src[i]);
    }
}

// ---------------- fp32 -> fp16 conversions (k-padded to 512) ----------------
__global__ __launch_bounds__(256) void convert_x(const float* __restrict__ X, f16* __restrict__ X16) {
    long i = (long)blockIdx.x * 256 + threadIdx.x;   // over N_NODES*K_PAD
    int n = (int)(i >> 9), k = (int)(i & (K_PAD - 1));
    X16[i] = (k < D_IN_K) ? (f16)X[(long)n * D_IN_K + k] : (f16)0.f;
}

__global__ __launch_bounds__(256) void convert_w(const float* __restrict__ W, f16* __restrict__ W16) {
    int i = blockIdx.x * 256 + threadIdx.x;          // over H_DIM*K_PAD
    int n = i >> 9, k = i & (K_PAD - 1);
    W16[i] = (k < D_IN_K) ? (f16)W[n * D_IN_K + k] : (f16)0.f;
}

// ---------------- init GEMM via MFMA, LDS-staged W ----------------
#define W_STRIDE 520
__global__ __launch_bounds__(256) void mfma_gemm2(const f16* __restrict__ X16,
                                                  const f16* __restrict__ W16,
                                                  const float* __restrict__ bias,
                                                  u16* __restrict__ out) {
    __shared__ __align__(16) f16 wlds[64 * W_STRIDE];
    int tid  = threadIdx.x;
    int wl   = tid >> 6;
    int lane = tid & 63;
    int m    = lane & 15;
    int quad = lane >> 4;

    int node = blockIdx.x * 64 + wl * 16 + m;
    int nodec = (node < N_NODES) ? node : N_NODES - 1;

    f16x8 a[16];
    const f16* ap = X16 + (long)nodec * K_PAD + quad * 8;
#pragma unroll
    for (int kc = 0; kc < 16; kc++) a[kc] = *(const f16x8*)(ap + kc * 32);

    for (int p = 0; p < 4; p++) {
        __syncthreads();
        for (int idx = tid; idx < 64 * 64; idx += 256) {
            int row = idx >> 6, c = idx & 63;
            *(f16x8*)&wlds[row * W_STRIDE + c * 8] = *(const f16x8*)&W16[(p * 64 + row) * K_PAD + c * 8];
        }
        __syncthreads();

        f32x4 acc[4];
#pragma unroll
        for (int t = 0; t < 4; t++) acc[t] = (f32x4){0.f, 0.f, 0.f, 0.f};

        for (int kc = 0; kc < 16; kc++) {
#pragma unroll
            for (int t = 0; t < 4; t++) {
                f16x8 b = *(const f16x8*)&wlds[(t * 16 + m) * W_STRIDE + kc * 32 + quad * 8];
                acc[t] = __builtin_amdgcn_mfma_f32_16x16x32_f16(a[kc], b, acc[t], 0, 0, 0);
            }
        }

        int nb = blockIdx.x * 64 + wl * 16 + quad * 4;
#pragma unroll
        for (int t = 0; t < 4; t++) {
            int h = p * 64 + t * 16 + m;
            float bv = bias[h];
#pragma unroll
            for (int r = 0; r < 4; r++) {
                int nrow = nb + r;
                if (nrow < N_NODES) out[(long)nrow * H_DIM + h] = f2h(acc[t][r] + bv);
            }
        }
    }
}

// ---------------- al/ar for layer 0 (from x0) ----------------
__global__ __launch_bounds__(256) void alar_kernel(const u16* __restrict__ x,
                                                   const float* __restrict__ attl,
                                                   const float* __restrict__ attr,
                                                   float* __restrict__ al, float* __restrict__ ar, int n) {
    int w = (blockIdx.x * blockDim.x + threadIdx.x) >> 6;
    int lane = threadIdx.x & 63;
    if (w >= n) return;
    int col = lane * 4;
    ushort4 xv = *(const ushort4*)(x + (long)w * H_DIM + col);
    float4 lv = *(const float4*)(attl + col);
    float4 rv = *(const float4*)(attr + col);
    float x0 = h2f(xv.x), x1 = h2f(xv.y), x2 = h2f(xv.z), x3 = h2f(xv.w);
    float pl = x0 * lv.x + x1 * lv.y + x2 * lv.z + x3 * lv.w;
    float pr = x0 * rv.x + x1 * rv.y + x2 * rv.z + x3 * rv.w;
#pragma unroll
    for (int off = 32; off >= 1; off >>= 1) {
        pl += __shfl_xor(pl, off);
        pr += __shfl_xor(pr, off);
    }
    if (lane == 0) { al[w] = pl; ar[w] = pr; }
}

// ---------------- layer v2: half-wave gather + relu/LN + fused next al/ar ----------------
__global__ __launch_bounds__(256) void layer_kernel2(const u16* __restrict__ xin,
                                                     const u16* __restrict__ x0,
                                                     const float* __restrict__ alIn,
                                                     float* __restrict__ alOut,
                                                     float* __restrict__ ar,
                                                     const int* __restrict__ row_ptr,
                                                     const int* __restrict__ srcS,
                                                     const float* __restrict__ g,
                                                     const float* __restrict__ b,
                                                     const float* __restrict__ attlN,
                                                     const float* __restrict__ attrN,
                                                     u16* __restrict__ xout, int n, int do_ln) {
    int w = (blockIdx.x * blockDim.x + threadIdx.x) >> 6;
    int lane = threadIdx.x & 63;
    if (w >= n) return;
    int half = lane >> 5;
    int sub  = lane & 31;
    int col  = sub * 8;

    float arn = ar[w];
    float aself = ALPHA_W * tanhf(alIn[w] + arn);

    float acc[8];
    if (half == 0) {
        u16x8 xs  = *(const u16x8*)(xin + (long)w * H_DIM + col);
        u16x8 x0v = *(const u16x8*)(x0  + (long)w * H_DIM + col);
#pragma unroll
        for (int k = 0; k < 8; k++) acc[k] = aself * h2f(xs[k]) + EPS_W * h2f(x0v[k]);
    } else {
#pragma unroll
        for (int k = 0; k < 8; k++) acc[k] = 0.f;
    }

    int e0 = row_ptr[w], e1 = row_ptr[w + 1];
    for (int base = e0; base < e1; base += 64) {
        int cnt = e1 - base; if (cnt > 64) cnt = 64;
        int s = 0; float a = 0.f;
        if (lane < cnt) {
            s = clampN(srcS[base + lane]);
            a = GAMMA_W * tanhf(alIn[s] + arn);
        }
        for (int j = 0; j < cnt; j += 2) {
            int idx = j + half;
            int sj  = __shfl(s, idx);
            float aj = __shfl(a, idx);
            u16x8 xv = *(const u16x8*)(xin + (long)sj * H_DIM + col);
#pragma unroll
            for (int k = 0; k < 8; k++) acc[k] = fmaf(aj, h2f(xv[k]), acc[k]);
        }
    }

#pragma unroll
    for (int k = 0; k < 8; k++) acc[k] += __shfl(acc[k], lane ^ 32);

    u16x8 o;
    if (do_ln) {
        float v[8];
        float sum = 0.f, sq = 0.f;
#pragma unroll
        for (int k = 0; k < 8; k++) {
            v[k] = fmaxf(acc[k], 0.f);
            sum += v[k];
            sq  += v[k] * v[k];
        }
#pragma unroll
        for (int off = 16; off >= 1; off >>= 1) {
            sum += __shfl_xor(sum, off);
            sq  += __shfl_xor(sq, off);
        }
        float mu = sum * (1.f / 256.f);
        float var = fmaxf(sq * (1.f / 256.f) - mu * mu, 0.f);
        float rstd = rsqrtf(var + LN_EPS_W);
        float4 ga = *(const float4*)(g + col);
        float4 gb = *(const float4*)(g + col + 4);
        float4 ba = *(const float4*)(b + col);
        float4 bb = *(const float4*)(b + col + 4);
        float gg[8] = {ga.x, ga.y, ga.z, ga.w, gb.x, gb.y, gb.z, gb.w};
        float bbv[8] = {ba.x, ba.y, ba.z, ba.w, bb.x, bb.y, bb.z, bb.w};
        float pl = 0.f, pr = 0.f;
        float4 la = *(const float4*)(attlN + col);
        float4 lb = *(const float4*)(attlN + col + 4);
        float4 ra = *(const float4*)(attrN + col);
        float4 rb = *(const float4*)(attrN + col + 4);
        float ll[8] = {la.x, la.y, la.z, la.w, lb.x, lb.y, lb.z, lb.w};
        float rr[8] = {ra.x, ra.y, ra.z, ra.w, rb.x, rb.y, rb.z, rb.w};
#pragma unroll
        for (int k = 0; k < 8; k++) {
            float val = (v[k] - mu) * rstd * gg[k] + bbv[k];
            o[k] = f2h(val);
            pl += val * ll[k];
            pr += val * rr[k];
        }
#pragma unroll
        for (int off = 16; off >= 1; off >>= 1) {
            pl += __shfl_xor(pl, off);
            pr += __shfl_xor(pr, off);
        }
        if (lane == 0) { alOut[w] = pl; ar[w] = pr; }
    } else {
#pragma unroll
        for (int k = 0; k < 8; k++) o[k] = f2h(acc[k]);
    }
    if (half == 0) *(u16x8*)(xout + (long)w * H_DIM + col) = o;
}

// ---------------- final: emb = x @ W_last^T + b_last ; log_softmax (fp32 OUT) ----------------
__global__ __launch_bounds__(256) void final_kernel(const u16* __restrict__ x,
                                                    const float* __restrict__ Wl,
                                                    const float* __restrict__ bl,
                                                    float* __restrict__ out, int n) {
    __shared__ float Ws[N_CLS * H_DIM];
    for (int i = threadIdx.x; i < N_CLS * H_DIM; i += blockDim.x) Ws[i] = Wl[i];
    __syncthreads();

    int w = (blockIdx.x * blockDim.x + threadIdx.x) >> 6;
    int lane = threadIdx.x & 63;
    if (w >= n) return;
    int col = lane * 4;
    ushort4 xv = *(const ushort4*)(x + (long)w * H_DIM + col);
    float x0 = h2f(xv.x), x1 = h2f(xv.y), x2 = h2f(xv.z), x3 = h2f(xv.w);

    float p[N_CLS];
#pragma unroll
    for (int c = 0; c < N_CLS; c++) {
        const float* wr = &Ws[c * H_DIM + col];
        p[c] = x0 * wr[0] + x1 * wr[1] + x2 * wr[2] + x3 * wr[3];
    }
#pragma unroll
    for (int off = 32; off >= 1; off >>= 1) {
#pragma unroll
        for (int c = 0; c < N_CLS; c++) p[c] += __shfl_xor(p[c], off);
    }
    if (lane == 0) {
        float e[N_CLS];
        float m = -1e30f;
#pragma unroll
        for (int c = 0; c < N_CLS; c++) {
            e[c] = p[c] + bl[c];
            m = fmaxf(m, e[c]);
        }
        float s = 0.f;
#pragma unroll
        for (int c = 0; c < N_CLS; c++) s += expf(e[c] - m);
        float lse = logf(s);
#pragma unroll
        for (int c = 0; c < N_CLS; c++) {
            out[(long)w * N_CLS + c] = e[c];
            out[(long)N_NODES * N_CLS + (long)w * N_CLS + c] = e[c] - m - lse;
        }
    }
}

extern "C" void kernel_launch(void* const* d_in, const int* in_sizes, int n_in,
                              void* d_out, int out_size, void* d_ws, size_t ws_size,
                              hipStream_t stream) {
    const float* x_in   = (const float*)d_in[0];
    const int*   ei     = (const int*)d_in[1];     // [2][E] planar int32
    const float* W_init = (const float*)d_in[2];
    const float* b_init = (const float*)d_in[3];
    const float* att_l  = (const float*)d_in[4];
    const float* att_r  = (const float*)d_in[5];
    const float* ln_g   = (const float*)d_in[6];
    const float* ln_b   = (const float*)d_in[7];
    const float* W_last = (const float*)d_in[8];
    const float* b_last = (const float*)d_in[9];
    float* out = (float*)d_out;

    // workspace layout (80,802,176 B total)
    const size_t OFF_X0  = 0;                  // 25,600,000
    const size_t OFF_XA  = 25600000;           // 25,600,000 (X16 spans XA+XB during init)
    const size_t OFF_XB  = 51200000;           // 25,600,000
    const size_t OFF_AL  = 76800000;           //    200,000 (W16 overlays AL/AR during init)
    const size_t OFF_AR  = 77000000;           //    200,000
    const size_t OFF_DEG = 77200000;           //    200,000 (al2 after CSR build)
    const size_t OFF_RP  = 77400000;           //    200,064
    const size_t OFF_SRC = 77600064;           //  3,200,000
    const size_t OFF_BS  = 80800064;           //      1,024 (scan block sums, 196 ints padded)
    const size_t OFF_BO  = 80801088;           //      1,024 (scan block offsets)
    const size_t WS_NEED = 80802112;

    if (ws_size < WS_NEED) {
        sentinel_kernel<<<(out_size + 255) / 256, 256, 0, stream>>>(out, out_size);
        return;
    }

    char* ws = (char*)d_ws;
    u16* x0  = (u16*)(ws + OFF_X0);
    u16* xA  = (u16*)(ws + OFF_XA);
    u16* xB  = (u16*)(ws + OFF_XB);
    f16* X16 = (f16*)(ws + OFF_XA);
    f16* W16 = (f16*)(ws + OFF_AL);
    float* al  = (float*)(ws + OFF_AL);
    float* ar  = (float*)(ws + OFF_AR);
    float* al2 = (float*)(ws + OFF_DEG);
    int* deg     = (int*)(ws + OFF_DEG);
    int* row_ptr = (int*)(ws + OFF_RP);
    int* srcS    = (int*)(ws + OFF_SRC);
    int* bsum    = (int*)(ws + OFF_BS);
    int* boff    = (int*)(ws + OFF_BO);

    const int* e_src = ei;
    const int* e_dst = ei + N_EDGES;

    // --- CSR build (by dst), two-level scan ---
    int zb = (N_NODES + 255) / 256;
    zero_kernel<<<zb, 256, 0, stream>>>(deg, N_NODES);
    int eb = (N_EDGES + 255) / 256;
    hist_kernel<<<eb, 256, 0, stream>>>(e_dst, deg, N_EDGES);
    scan_a<<<SCAN_NB, SCAN_B, 0, stream>>>(deg, row_ptr, bsum);
    scan_b<<<1, SCAN_B, 0, stream>>>(bsum, boff, row_ptr);
    scan_c<<<SCAN_NB, SCAN_B, 0, stream>>>(row_ptr, boff);
    scatter_kernel<<<eb, 256, 0, stream>>>(e_src, e_dst, row_ptr, deg, srcS, N_EDGES);

    // --- init linear: fp16 convert + LDS-staged MFMA GEMM ---
    convert_x<<<(N_NODES * K_PAD) / 256, 256, 0, stream>>>(x_in, X16);
    convert_w<<<(H_DIM * K_PAD) / 256, 256, 0, stream>>>(W_init, W16);
    mfma_gemm2<<<(N_NODES + 63) / 64, 256, 0, stream>>>(X16, W16, b_init, x0);

    // --- al/ar for layer 0 ---
    int nb = (N_NODES * 64 + 255) / 256;   // one wave per node
    alar_kernel<<<nb, 256, 0, stream>>>(x0, att_l, att_r, al, ar, N_NODES);

    // --- layers (al ping-pongs al <-> al2; ar in-place) ---
    const u16* bufs_in[4]   = {x0, xA, xB, xA};
    u16* bufs_out[4]        = {xA, xB, xA, xB};
    const float* al_in[4]   = {al, al2, al, al2};
    float* al_out[4]        = {al2, al, al2, al};
    for (int i = 0; i < 4; i++) {
        int nxt = (i < 3) ? (i + 1) : i;
        layer_kernel2<<<nb, 256, 0, stream>>>(bufs_in[i], x0, al_in[i], al_out[i], ar,
                                              row_ptr, srcS,
                                              ln_g + i * H_DIM, ln_b + i * H_DIM,
                                              att_l + nxt * H_DIM, att_r + nxt * H_DIM,
                                              bufs_out[i], N_NODES, (i < 3) ? 1 : 0);
    }

    // --- final linear + log_softmax ---
    final_kernel<<<nb, 256, 0, stream>>>(xB, W_last, b_last, out, N_NODES);
}

// Round 13
// 593.309 us; speedup vs baseline: 4.5537x; 1.0957x over previous
//
#include <hip/hip_runtime.h>
#include <hip/hip_fp16.h>

#define N_NODES 50000
#define N_EDGES 800000
#define D_IN_K  500
#define K_PAD   512
#define H_DIM   256
#define N_CLS   7
#define ALPHA_W 0.5f
#define GAMMA_W 0.5f
#define EPS_W   0.1f
#define LN_EPS_W 1e-5f

#define SCAN_B 256
#define SCAN_NB ((N_NODES + SCAN_B - 1) / SCAN_B)   // 196

typedef unsigned short u16;
typedef unsigned int   u32;
typedef _Float16 f16;
typedef __attribute__((ext_vector_type(8))) _Float16 f16x8;
typedef __attribute__((ext_vector_type(4))) float    f32x4;
typedef __attribute__((ext_vector_type(8))) unsigned short u16x8;

__device__ __forceinline__ float h2f(u16 v) {
    __half h;
    *reinterpret_cast<u16*>(&h) = v;
    return __half2float(h);
}
__device__ __forceinline__ u16 f2h(float f) {
    __half h = __float2half_rn(f);
    return *reinterpret_cast<u16*>(&h);
}
__device__ __forceinline__ int clampN(int v) {
    return (v < 0) ? 0 : ((v >= N_NODES) ? N_NODES - 1 : v);
}

// ---------------- fallback sentinel (fp32 output) ----------------
__global__ __launch_bounds__(256) void sentinel_kernel(float* out, int n) {
    int i = blockIdx.x * blockDim.x + threadIdx.x;
    if (i < n) out[i] = 2.0f;
}

// ---------------- CSR build ----------------
__global__ __launch_bounds__(256) void zero_kernel(int* p, int n) {
    int i = blockIdx.x * blockDim.x + threadIdx.x;
    if (i < n) p[i] = 0;
}

__global__ __launch_bounds__(256) void hist_kernel(const int* __restrict__ dst, int* __restrict__ deg, int e) {
    int i = blockIdx.x * blockDim.x + threadIdx.x;
    if (i < e) atomicAdd(&deg[clampN(dst[i])], 1);
}

__global__ __launch_bounds__(SCAN_B) void scan_a(const int* __restrict__ deg, int* __restrict__ row_ptr,
                                                 int* __restrict__ bsum) {
    __shared__ int sdata[SCAN_B];
    int t = threadIdx.x;
    int i = blockIdx.x * SCAN_B + t;
    int v = (i < N_NODES) ? deg[i] : 0;
    sdata[t] = v;
    __syncthreads();
#pragma unroll
    for (int off = 1; off < SCAN_B; off <<= 1) {
        int a = (t >= off) ? sdata[t - off] : 0;
        __syncthreads();
        sdata[t] += a;
        __syncthreads();
    }
    if (i < N_NODES) row_ptr[i] = sdata[t] - v;
    if (t == SCAN_B - 1) bsum[blockIdx.x] = sdata[t];
}

__global__ __launch_bounds__(SCAN_B) void scan_b(int* __restrict__ bsum, int* __restrict__ boff,
                                                 int* __restrict__ row_ptr) {
    __shared__ int sdata[SCAN_B];
    int t = threadIdx.x;
    int v = (t < SCAN_NB) ? bsum[t] : 0;
    sdata[t] = v;
    __syncthreads();
#pragma unroll
    for (int off = 1; off < SCAN_B; off <<= 1) {
        int a = (t >= off) ? sdata[t - off] : 0;
        __syncthreads();
        sdata[t] += a;
        __syncthreads();
    }
    if (t < SCAN_NB) boff[t] = sdata[t] - v;
    if (t == SCAN_B - 1) row_ptr[N_NODES] = sdata[t];
}

__global__ __launch_bounds__(SCAN_B) void scan_c(int* __restrict__ row_ptr, const int* __restrict__ boff) {
    int i = blockIdx.x * SCAN_B + threadIdx.x;
    if (i < N_NODES) row_ptr[i] += boff[blockIdx.x];
}

__global__ __launch_bounds__(256) void scatter_kernel(const int* __restrict__ src, const int* __restrict__ dst,
                                                      const int* __restrict__ row_ptr, int* __restrict__ deg,
                                                      int* __restrict__ srcS, int e) {
    int i = blockIdx.x * blockDim.x + threadIdx.x;
    if (i < e) {
        int d = clampN(dst[i]);
        int old = atomicSub(&deg[d], 1);
        int pos = row_ptr[d] + old - 1;
        if (pos >= 0 && pos < e) srcS[pos] = clampN(src[i]);
    }
}

// ---------------- fp32 -> fp16 conversion for W (k-padded to 512) ----------------
__global__ __launch_bounds__(256) void convert_w(const float* __restrict__ W, f16* __restrict__ W16) {
    int i = blockIdx.x * 256 + threadIdx.x;          // over H_DIM*K_PAD
    int n = i >> 9, k = i & (K_PAD - 1);
    W16[i] = (k < D_IN_K) ? (f16)W[n * D_IN_K + k] : (f16)0.f;
}

// ---------------- init GEMM via MFMA, LDS-staged W, fp32 X converted in-register ----------------
#define W_STRIDE 520
__global__ __launch_bounds__(256) void mfma_gemm2(const float* __restrict__ X,
                                                  const f16* __restrict__ W16,
                                                  const float* __restrict__ bias,
                                                  u16* __restrict__ out) {
    __shared__ __align__(16) f16 wlds[64 * W_STRIDE];
    int tid  = threadIdx.x;
    int wl   = tid >> 6;
    int lane = tid & 63;
    int m    = lane & 15;
    int quad = lane >> 4;

    int node = blockIdx.x * 64 + wl * 16 + m;
    int nodec = (node < N_NODES) ? node : N_NODES - 1;

    // load + convert A-fragments once (X rows are 2000 B -> 16B-aligned)
    f16x8 a[16];
    const float* ap = X + (long)nodec * D_IN_K;
#pragma unroll
    for (int kc = 0; kc < 16; kc++) {
        int kbase = kc * 32 + quad * 8;
        f16x8 av;
        if (kbase + 8 <= D_IN_K) {
            float4 lo = *(const float4*)(ap + kbase);
            float4 hi = *(const float4*)(ap + kbase + 4);
            av[0] = (f16)lo.x; av[1] = (f16)lo.y; av[2] = (f16)lo.z; av[3] = (f16)lo.w;
            av[4] = (f16)hi.x; av[5] = (f16)hi.y; av[6] = (f16)hi.z; av[7] = (f16)hi.w;
        } else {
#pragma unroll
            for (int t = 0; t < 8; t++)
                av[t] = (kbase + t < D_IN_K) ? (f16)ap[kbase + t] : (f16)0.f;
        }
        a[kc] = av;
    }

    for (int p = 0; p < 4; p++) {
        __syncthreads();
        for (int idx = tid; idx < 64 * 64; idx += 256) {
            int row = idx >> 6, c = idx & 63;
            *(f16x8*)&wlds[row * W_STRIDE + c * 8] = *(const f16x8*)&W16[(p * 64 + row) * K_PAD + c * 8];
        }
        __syncthreads();

        f32x4 acc[4];
#pragma unroll
        for (int t = 0; t < 4; t++) acc[t] = (f32x4){0.f, 0.f, 0.f, 0.f};

        for (int kc = 0; kc < 16; kc++) {
#pragma unroll
            for (int t = 0; t < 4; t++) {
                f16x8 b = *(const f16x8*)&wlds[(t * 16 + m) * W_STRIDE + kc * 32 + quad * 8];
                acc[t] = __builtin_amdgcn_mfma_f32_16x16x32_f16(a[kc], b, acc[t], 0, 0, 0);
            }
        }

        int nb = blockIdx.x * 64 + wl * 16 + quad * 4;
#pragma unroll
        for (int t = 0; t < 4; t++) {
            int h = p * 64 + t * 16 + m;
            float bv = bias[h];
#pragma unroll
            for (int r = 0; r < 4; r++) {
                int nrow = nb + r;
                if (nrow < N_NODES) out[(long)nrow * H_DIM + h] = f2h(acc[t][r] + bv);
            }
        }
    }
}

// ---------------- al/ar for layer 0 (from x0) ----------------
__global__ __launch_bounds__(256) void alar_kernel(const u16* __restrict__ x,
                                                   const float* __restrict__ attl,
                                                   const float* __restrict__ attr,
                                                   float* __restrict__ al, float* __restrict__ ar, int n) {
    int w = (blockIdx.x * blockDim.x + threadIdx.x) >> 6;
    int lane = threadIdx.x & 63;
    if (w >= n) return;
    int col = lane * 4;
    ushort4 xv = *(const ushort4*)(x + (long)w * H_DIM + col);
    float4 lv = *(const float4*)(attl + col);
    float4 rv = *(const float4*)(attr + col);
    float x0 = h2f(xv.x), x1 = h2f(xv.y), x2 = h2f(xv.z), x3 = h2f(xv.w);
    float pl = x0 * lv.x + x1 * lv.y + x2 * lv.z + x3 * lv.w;
    float pr = x0 * rv.x + x1 * rv.y + x2 * rv.z + x3 * rv.w;
#pragma unroll
    for (int off = 32; off >= 1; off >>= 1) {
        pl += __shfl_xor(pl, off);
        pr += __shfl_xor(pr, off);
    }
    if (lane == 0) { al[w] = pl; ar[w] = pr; }
}

// ---------------- layer v3: 4-deep pipelined gather; mode 0 = relu/LN + fused next al/ar,
//                  mode 1 = fused final linear + log_softmax (no x write) ----------------
__global__ __launch_bounds__(256) void layer_kernel3(const u16* __restrict__ xin,
                                                     const u16* __restrict__ x0,
                                                     const float* __restrict__ alIn,
                                                     float* __restrict__ alOut,
                                                     float* __restrict__ ar,
                                                     const int* __restrict__ row_ptr,
                                                     const int* __restrict__ srcS,
                                                     const float* __restrict__ g,
                                                     const float* __restrict__ b,
                                                     const float* __restrict__ attlN,
                                                     const float* __restrict__ attrN,
                                                     u16* __restrict__ xout,
                                                     const float* __restrict__ Wl,
                                                     const float* __restrict__ bl,
                                                     float* __restrict__ outF,
                                                     int n, int mode) {
    int w = (blockIdx.x * blockDim.x + threadIdx.x) >> 6;
    int lane = threadIdx.x & 63;
    if (w >= n) return;
    int half = lane >> 5;
    int sub  = lane & 31;
    int col  = sub * 8;

    float arn = ar[w];
    float aself = ALPHA_W * tanhf(alIn[w] + arn);

    float acc[8];
    if (half == 0) {
        u16x8 xs  = *(const u16x8*)(xin + (long)w * H_DIM + col);
        u16x8 x0v = *(const u16x8*)(x0  + (long)w * H_DIM + col);
#pragma unroll
        for (int k = 0; k < 8; k++) acc[k] = aself * h2f(xs[k]) + EPS_W * h2f(x0v[k]);
    } else {
#pragma unroll
        for (int k = 0; k < 8; k++) acc[k] = 0.f;
    }

    int e0 = row_ptr[w], e1 = row_ptr[w + 1];
    for (int base = e0; base < e1; base += 64) {
        int cnt = e1 - base; if (cnt > 64) cnt = 64;
        int s = 0; float a = 0.f;
        if (lane < cnt) {
            s = clampN(srcS[base + lane]);
            a = GAMMA_W * tanhf(alIn[s] + arn);
        }
        // 8 edges per iteration; 4 per half; all 4 loads issued before the FMAs.
        // idx >= cnt pulls s=0,a=0 -> contributes 0 (harmless extra load of row 0).
        for (int j = 0; j < cnt; j += 8) {
            int i0 = j + half, i1 = j + 2 + half, i2 = j + 4 + half, i3 = j + 6 + half;
            int s0 = __shfl(s, i0), s1 = __shfl(s, i1), s2 = __shfl(s, i2), s3 = __shfl(s, i3);
            float c0 = __shfl(a, i0), c1 = __shfl(a, i1), c2 = __shfl(a, i2), c3 = __shfl(a, i3);
            u16x8 v0 = *(const u16x8*)(xin + (long)s0 * H_DIM + col);
            u16x8 v1 = *(const u16x8*)(xin + (long)s1 * H_DIM + col);
            u16x8 v2 = *(const u16x8*)(xin + (long)s2 * H_DIM + col);
            u16x8 v3 = *(const u16x8*)(xin + (long)s3 * H_DIM + col);
#pragma unroll
            for (int k = 0; k < 8; k++) {
                acc[k] = fmaf(c0, h2f(v0[k]), acc[k]);
                acc[k] = fmaf(c1, h2f(v1[k]), acc[k]);
                acc[k] = fmaf(c2, h2f(v2[k]), acc[k]);
                acc[k] = fmaf(c3, h2f(v3[k]), acc[k]);
            }
        }
    }

    // combine halves
#pragma unroll
    for (int k = 0; k < 8; k++) acc[k] += __shfl(acc[k], lane ^ 32);

    if (mode == 0) {
        float v[8];
        float sum = 0.f, sq = 0.f;
#pragma unroll
        for (int k = 0; k < 8; k++) {
            v[k] = fmaxf(acc[k], 0.f);
            sum += v[k];
            sq  += v[k] * v[k];
        }
#pragma unroll
        for (int off = 16; off >= 1; off >>= 1) {
            sum += __shfl_xor(sum, off);
            sq  += __shfl_xor(sq, off);
        }
        float mu = sum * (1.f / 256.f);
        float var = fmaxf(sq * (1.f / 256.f) - mu * mu, 0.f);
        float rstd = rsqrtf(var + LN_EPS_W);
        float4 ga = *(const float4*)(g + col);
        float4 gb = *(const float4*)(g + col + 4);
        float4 ba = *(const float4*)(b + col);
        float4 bb = *(const float4*)(b + col + 4);
        float gg[8]  = {ga.x, ga.y, ga.z, ga.w, gb.x, gb.y, gb.z, gb.w};
        float bbv[8] = {ba.x, ba.y, ba.z, ba.w, bb.x, bb.y, bb.z, bb.w};
        float4 la = *(const float4*)(attlN + col);
        float4 lb = *(const float4*)(attlN + col + 4);
        float4 ra = *(const float4*)(attrN + col);
        float4 rb = *(const float4*)(attrN + col + 4);
        float ll[8] = {la.x, la.y, la.z, la.w, lb.x, lb.y, lb.z, lb.w};
        float rr[8] = {ra.x, ra.y, ra.z, ra.w, rb.x, rb.y, rb.z, rb.w};
        float pl = 0.f, pr = 0.f;
        u16x8 o;
#pragma unroll
        for (int k = 0; k < 8; k++) {
            float val = (v[k] - mu) * rstd * gg[k] + bbv[k];
            o[k] = f2h(val);
            pl += val * ll[k];
            pr += val * rr[k];
        }
#pragma unroll
        for (int off = 16; off >= 1; off >>= 1) {
            pl += __shfl_xor(pl, off);
            pr += __shfl_xor(pr, off);
        }
        if (lane == 0) { alOut[w] = pl; ar[w] = pr; }
        if (half == 0) *(u16x8*)(xout + (long)w * H_DIM + col) = o;
    } else {
        // fused final: emb = acc . W_last^T + b_last ; log_softmax
        float p[N_CLS];
#pragma unroll
        for (int c = 0; c < N_CLS; c++) {
            const float* wr = Wl + c * H_DIM + col;
            float4 wa = *(const float4*)(wr);
            float4 wb = *(const float4*)(wr + 4);
            p[c] = acc[0] * wa.x + acc[1] * wa.y + acc[2] * wa.z + acc[3] * wa.w
                 + acc[4] * wb.x + acc[5] * wb.y + acc[6] * wb.z + acc[7] * wb.w;
        }
#pragma unroll
        for (int off = 16; off >= 1; off >>= 1) {
#pragma unroll
            for (int c = 0; c < N_CLS; c++) p[c] += __shfl_xor(p[c], off);
        }
        if (lane == 0) {
            float e[N_CLS];
            float m = -1e30f;
#pragma unroll
            for (int c = 0; c < N_CLS; c++) {
                e[c] = p[c] + bl[c];
                m = fmaxf(m, e[c]);
            }
            float sx = 0.f;
#pragma unroll
            for (int c = 0; c < N_CLS; c++) sx += expf(e[c] - m);
            float lse = logf(sx);
#pragma unroll
            for (int c = 0; c < N_CLS; c++) {
                outF[(long)w * N_CLS + c] = e[c];
                outF[(long)N_NODES * N_CLS + (long)w * N_CLS + c] = e[c] - m - lse;
            }
        }
    }
}

extern "C" void kernel_launch(void* const* d_in, const int* in_sizes, int n_in,
                              void* d_out, int out_size, void* d_ws, size_t ws_size,
                              hipStream_t stream) {
    const float* x_in   = (const float*)d_in[0];
    const int*   ei     = (const int*)d_in[1];     // [2][E] planar int32
    const float* W_init = (const float*)d_in[2];
    const float* b_init = (const float*)d_in[3];
    const float* att_l  = (const float*)d_in[4];
    const float* att_r  = (const float*)d_in[5];
    const float* ln_g   = (const float*)d_in[6];
    const float* ln_b   = (const float*)d_in[7];
    const float* W_last = (const float*)d_in[8];
    const float* b_last = (const float*)d_in[9];
    float* out = (float*)d_out;

    // workspace layout (80,802,112 B total)
    const size_t OFF_X0  = 0;                  // 25,600,000
    const size_t OFF_XA  = 25600000;           // 25,600,000
    const size_t OFF_XB  = 51200000;           // 25,600,000
    const size_t OFF_AL  = 76800000;           //    200,000 (W16 overlays AL/AR during init)
    const size_t OFF_AR  = 77000000;           //    200,000
    const size_t OFF_DEG = 77200000;           //    200,000 (al2 after CSR build)
    const size_t OFF_RP  = 77400000;           //    200,064
    const size_t OFF_SRC = 77600064;           //  3,200,000
    const size_t OFF_BS  = 80800064;           //      1,024
    const size_t OFF_BO  = 80801088;           //      1,024
    const size_t WS_NEED = 80802112;

    if (ws_size < WS_NEED) {
        sentinel_kernel<<<(out_size + 255) / 256, 256, 0, stream>>>(out, out_size);
        return;
    }

    char* ws = (char*)d_ws;
    u16* x0  = (u16*)(ws + OFF_X0);
    u16* xA  = (u16*)(ws + OFF_XA);
    u16* xB  = (u16*)(ws + OFF_XB);
    f16* W16 = (f16*)(ws + OFF_AL);
    float* al  = (float*)(ws + OFF_AL);
    float* ar  = (float*)(ws + OFF_AR);
    float* al2 = (float*)(ws + OFF_DEG);
    int* deg     = (int*)(ws + OFF_DEG);
    int* row_ptr = (int*)(ws + OFF_RP);
    int* srcS    = (int*)(ws + OFF_SRC);
    int* bsum    = (int*)(ws + OFF_BS);
    int* boff    = (int*)(ws + OFF_BO);

    const int* e_src = ei;
    const int* e_dst = ei + N_EDGES;

    // --- CSR build (by dst), two-level scan ---
    int zb = (N_NODES + 255) / 256;
    zero_kernel<<<zb, 256, 0, stream>>>(deg, N_NODES);
    int eb = (N_EDGES + 255) / 256;
    hist_kernel<<<eb, 256, 0, stream>>>(e_dst, deg, N_EDGES);
    scan_a<<<SCAN_NB, SCAN_B, 0, stream>>>(deg, row_ptr, bsum);
    scan_b<<<1, SCAN_B, 0, stream>>>(bsum, boff, row_ptr);
    scan_c<<<SCAN_NB, SCAN_B, 0, stream>>>(row_ptr, boff);
    scatter_kernel<<<eb, 256, 0, stream>>>(e_src, e_dst, row_ptr, deg, srcS, N_EDGES);

    // --- init linear: W convert + MFMA GEMM (X converted in-kernel) ---
    convert_w<<<(H_DIM * K_PAD) / 256, 256, 0, stream>>>(W_init, W16);
    mfma_gemm2<<<(N_NODES + 63) / 64, 256, 0, stream>>>(x_in, W16, b_init, x0);

    // --- al/ar for layer 0 ---
    int nb = (N_NODES * 64 + 255) / 256;   // one wave per node
    alar_kernel<<<nb, 256, 0, stream>>>(x0, att_l, att_r, al, ar, N_NODES);

    // --- layers 0-2 (LN mode), layer 3 (fused final) ---
    const u16* bufs_in[4]   = {x0, xA, xB, xA};
    u16* bufs_out[4]        = {xA, xB, xA, xB};   // [3] unused
    const float* al_in[4]   = {al, al2, al, al2};
    float* al_out[4]        = {al2, al, al2, al};
    for (int i = 0; i < 4; i++) {
        int nxt = (i < 3) ? (i + 1) : i;
        layer_kernel3<<<nb, 256, 0, stream>>>(bufs_in[i], x0, al_in[i], al_out[i], ar,
                                              row_ptr, srcS,
                                              ln_g + i * H_DIM, ln_b + i * H_DIM,
                                              att_l + nxt * H_DIM, att_r + nxt * H_DIM,
                                              bufs_out[i], W_last, b_last, out,
                                              N_NODES, (i < 3) ? 0 : 1);
    }
}

// Round 14
// 573.709 us; speedup vs baseline: 4.7093x; 1.0342x over previous
//
#include <hip/hip_runtime.h>
#include <hip/hip_fp16.h>

#define N_NODES 50000
#define N_EDGES 800000
#define D_IN_K  500
#define K_PAD   512
#define H_DIM   256
#define N_CLS   7
#define ALPHA_W 0.5f
#define GAMMA_W 0.5f
#define EPS_W   0.1f
#define LN_EPS_W 1e-5f

#define SCAN_B 256
#define SCAN_NB ((N_NODES + SCAN_B - 1) / SCAN_B)   // 196

typedef unsigned short u16;
typedef unsigned int   u32;
typedef _Float16 f16;
typedef __attribute__((ext_vector_type(8))) _Float16 f16x8;
typedef __attribute__((ext_vector_type(4))) float    f32x4;
typedef __attribute__((ext_vector_type(8))) unsigned short u16x8;

__device__ __forceinline__ float h2f(u16 v) {
    __half h;
    *reinterpret_cast<u16*>(&h) = v;
    return __half2float(h);
}
__device__ __forceinline__ u16 f2h(float f) {
    __half h = __float2half_rn(f);
    return *reinterpret_cast<u16*>(&h);
}
__device__ __forceinline__ int clampN(int v) {
    return (v < 0) ? 0 : ((v >= N_NODES) ? N_NODES - 1 : v);
}

// ---------------- fallback sentinel (fp32 output) ----------------
__global__ __launch_bounds__(256) void sentinel_kernel(float* out, int n) {
    int i = blockIdx.x * blockDim.x + threadIdx.x;
    if (i < n) out[i] = 2.0f;
}

// ---------------- CSR build ----------------
__global__ __launch_bounds__(256) void zero_kernel(int* p, int n) {
    int i = blockIdx.x * blockDim.x + threadIdx.x;
    if (i < n) p[i] = 0;
}

__global__ __launch_bounds__(256) void hist_kernel(const int* __restrict__ dst, int* __restrict__ deg, int e) {
    int i = blockIdx.x * blockDim.x + threadIdx.x;
    if (i < e) atomicAdd(&deg[clampN(dst[i])], 1);
}

__global__ __launch_bounds__(SCAN_B) void scan_a(const int* __restrict__ deg, int* __restrict__ row_ptr,
                                                 int* __restrict__ bsum) {
    __shared__ int sdata[SCAN_B];
    int t = threadIdx.x;
    int i = blockIdx.x * SCAN_B + t;
    int v = (i < N_NODES) ? deg[i] : 0;
    sdata[t] = v;
    __syncthreads();
#pragma unroll
    for (int off = 1; off < SCAN_B; off <<= 1) {
        int a = (t >= off) ? sdata[t - off] : 0;
        __syncthreads();
        sdata[t] += a;
        __syncthreads();
    }
    if (i < N_NODES) row_ptr[i] = sdata[t] - v;
    if (t == SCAN_B - 1) bsum[blockIdx.x] = sdata[t];
}

__global__ __launch_bounds__(SCAN_B) void scan_b(int* __restrict__ bsum, int* __restrict__ boff,
                                                 int* __restrict__ row_ptr) {
    __shared__ int sdata[SCAN_B];
    int t = threadIdx.x;
    int v = (t < SCAN_NB) ? bsum[t] : 0;
    sdata[t] = v;
    __syncthreads();
#pragma unroll
    for (int off = 1; off < SCAN_B; off <<= 1) {
        int a = (t >= off) ? sdata[t - off] : 0;
        __syncthreads();
        sdata[t] += a;
        __syncthreads();
    }
    if (t < SCAN_NB) boff[t] = sdata[t] - v;
    if (t == SCAN_B - 1) row_ptr[N_NODES] = sdata[t];
}

__global__ __launch_bounds__(SCAN_B) void scan_c(int* __restrict__ row_ptr, const int* __restrict__ boff) {
    int i = blockIdx.x * SCAN_B + threadIdx.x;
    if (i < N_NODES) row_ptr[i] += boff[blockIdx.x];
}

__global__ __launch_bounds__(256) void scatter_kernel(const int* __restrict__ src, const int* __restrict__ dst,
                                                      const int* __restrict__ row_ptr, int* __restrict__ deg,
                                                      int* __restrict__ srcS, int e) {
    int i = blockIdx.x * blockDim.x + threadIdx.x;
    if (i < e) {
        int d = clampN(dst[i]);
        int old = atomicSub(&deg[d], 1);
        int pos = row_ptr[d] + old - 1;
        if (pos >= 0 && pos < e) srcS[pos] = clampN(src[i]);
    }
}

// ---------------- fp32 -> fp16 conversion for W (k-padded to 512) ----------------
__global__ __launch_bounds__(256) void convert_w(const float* __restrict__ W, f16* __restrict__ W16) {
    int i = blockIdx.x * 256 + threadIdx.x;          // over H_DIM*K_PAD
    int n = i >> 9, k = i & (K_PAD - 1);
    W16[i] = (k < D_IN_K) ? (f16)W[n * D_IN_K + k] : (f16)0.f;
}

// ---------------- init GEMM via MFMA: 8 phases x 32 W-rows in LDS (33 KB -> 4 blocks/CU) ----------------
#define W_STRIDE 520   // f16; 1040 B/row, 16B-aligned
__global__ __launch_bounds__(256) void mfma_gemm3(const float* __restrict__ X,
                                                  const f16* __restrict__ W16,
                                                  const float* __restrict__ bias,
                                                  u16* __restrict__ out) {
    __shared__ __align__(16) f16 wlds[32 * W_STRIDE];   // 33,280 B
    int tid  = threadIdx.x;
    int wl   = tid >> 6;
    int lane = tid & 63;
    int m    = lane & 15;
    int quad = lane >> 4;

    int node = blockIdx.x * 64 + wl * 16 + m;
    int nodec = (node < N_NODES) ? node : N_NODES - 1;

    // load + convert A-fragments once (fp32 X, rows 2000 B, 16B-aligned)
    f16x8 a[16];
    const float* ap = X + (long)nodec * D_IN_K;
#pragma unroll
    for (int kc = 0; kc < 16; kc++) {
        int kbase = kc * 32 + quad * 8;
        f16x8 av;
        if (kbase + 8 <= D_IN_K) {
            float4 lo = *(const float4*)(ap + kbase);
            float4 hi = *(const float4*)(ap + kbase + 4);
            av[0] = (f16)lo.x; av[1] = (f16)lo.y; av[2] = (f16)lo.z; av[3] = (f16)lo.w;
            av[4] = (f16)hi.x; av[5] = (f16)hi.y; av[6] = (f16)hi.z; av[7] = (f16)hi.w;
        } else {
#pragma unroll
            for (int t = 0; t < 8; t++)
                av[t] = (kbase + t < D_IN_K) ? (f16)ap[kbase + t] : (f16)0.f;
        }
        a[kc] = av;
    }

    for (int p = 0; p < 8; p++) {
        __syncthreads();
        // stage W rows p*32 .. p*32+31 (32 x 512 f16 = 32 KB)
        for (int idx = tid; idx < 32 * 64; idx += 256) {
            int row = idx >> 6, c = idx & 63;
            *(f16x8*)&wlds[row * W_STRIDE + c * 8] = *(const f16x8*)&W16[((p << 5) + row) * K_PAD + c * 8];
        }
        __syncthreads();

        f32x4 acc[2];
#pragma unroll
        for (int t = 0; t < 2; t++) acc[t] = (f32x4){0.f, 0.f, 0.f, 0.f};

        for (int kc = 0; kc < 16; kc++) {
#pragma unroll
            for (int t = 0; t < 2; t++) {
                f16x8 b = *(const f16x8*)&wlds[(t * 16 + m) * W_STRIDE + kc * 32 + quad * 8];
                acc[t] = __builtin_amdgcn_mfma_f32_16x16x32_f16(a[kc], b, acc[t], 0, 0, 0);
            }
        }

        int nb = blockIdx.x * 64 + wl * 16 + quad * 4;
#pragma unroll
        for (int t = 0; t < 2; t++) {
            int h = (p << 5) + t * 16 + m;
            float bv = bias[h];
#pragma unroll
            for (int r = 0; r < 4; r++) {
                int nrow = nb + r;
                if (nrow < N_NODES) out[(long)nrow * H_DIM + h] = f2h(acc[t][r] + bv);
            }
        }
    }
}

// ---------------- al/ar for layer 0 (from x0) ----------------
__global__ __launch_bounds__(256) void alar_kernel(const u16* __restrict__ x,
                                                   const float* __restrict__ attl,
                                                   const float* __restrict__ attr,
                                                   float* __restrict__ al, float* __restrict__ ar, int n) {
    int w = (blockIdx.x * blockDim.x + threadIdx.x) >> 6;
    int lane = threadIdx.x & 63;
    if (w >= n) return;
    int col = lane * 4;
    ushort4 xv = *(const ushort4*)(x + (long)w * H_DIM + col);
    float4 lv = *(const float4*)(attl + col);
    float4 rv = *(const float4*)(attr + col);
    float x0 = h2f(xv.x), x1 = h2f(xv.y), x2 = h2f(xv.z), x3 = h2f(xv.w);
    float pl = x0 * lv.x + x1 * lv.y + x2 * lv.z + x3 * lv.w;
    float pr = x0 * rv.x + x1 * rv.y + x2 * rv.z + x3 * rv.w;
#pragma unroll
    for (int off = 32; off >= 1; off >>= 1) {
        pl += __shfl_xor(pl, off);
        pr += __shfl_xor(pr, off);
    }
    if (lane == 0) { al[w] = pl; ar[w] = pr; }
}

// ---------------- layer v3: 4-deep pipelined gather; mode 0 = relu/LN + fused next al/ar,
//                  mode 1 = fused final linear + log_softmax (no x write) ----------------
__global__ __launch_bounds__(256) void layer_kernel3(const u16* __restrict__ xin,
                                                     const u16* __restrict__ x0,
                                                     const float* __restrict__ alIn,
                                                     float* __restrict__ alOut,
                                                     float* __restrict__ ar,
                                                     const int* __restrict__ row_ptr,
                                                     const int* __restrict__ srcS,
                                                     const float* __restrict__ g,
                                                     const float* __restrict__ b,
                                                     const float* __restrict__ attlN,
                                                     const float* __restrict__ attrN,
                                                     u16* __restrict__ xout,
                                                     const float* __restrict__ Wl,
                                                     const float* __restrict__ bl,
                                                     float* __restrict__ outF,
                                                     int n, int mode) {
    int w = (blockIdx.x * blockDim.x + threadIdx.x) >> 6;
    int lane = threadIdx.x & 63;
    if (w >= n) return;
    int half = lane >> 5;
    int sub  = lane & 31;
    int col  = sub * 8;

    float arn = ar[w];
    float aself = ALPHA_W * tanhf(alIn[w] + arn);

    float acc[8];
    if (half == 0) {
        u16x8 xs  = *(const u16x8*)(xin + (long)w * H_DIM + col);
        u16x8 x0v = *(const u16x8*)(x0  + (long)w * H_DIM + col);
#pragma unroll
        for (int k = 0; k < 8; k++) acc[k] = aself * h2f(xs[k]) + EPS_W * h2f(x0v[k]);
    } else {
#pragma unroll
        for (int k = 0; k < 8; k++) acc[k] = 0.f;
    }

    int e0 = row_ptr[w], e1 = row_ptr[w + 1];
    for (int base = e0; base < e1; base += 64) {
        int cnt = e1 - base; if (cnt > 64) cnt = 64;
        int s = 0; float a = 0.f;
        if (lane < cnt) {
            s = clampN(srcS[base + lane]);
            a = GAMMA_W * tanhf(alIn[s] + arn);
        }
        for (int j = 0; j < cnt; j += 8) {
            int i0 = j + half, i1 = j + 2 + half, i2 = j + 4 + half, i3 = j + 6 + half;
            int s0 = __shfl(s, i0), s1 = __shfl(s, i1), s2 = __shfl(s, i2), s3 = __shfl(s, i3);
            float c0 = __shfl(a, i0), c1 = __shfl(a, i1), c2 = __shfl(a, i2), c3 = __shfl(a, i3);
            u16x8 v0 = *(const u16x8*)(xin + (long)s0 * H_DIM + col);
            u16x8 v1 = *(const u16x8*)(xin + (long)s1 * H_DIM + col);
            u16x8 v2 = *(const u16x8*)(xin + (long)s2 * H_DIM + col);
            u16x8 v3 = *(const u16x8*)(xin + (long)s3 * H_DIM + col);
#pragma unroll
            for (int k = 0; k < 8; k++) {
                acc[k] = fmaf(c0, h2f(v0[k]), acc[k]);
                acc[k] = fmaf(c1, h2f(v1[k]), acc[k]);
                acc[k] = fmaf(c2, h2f(v2[k]), acc[k]);
                acc[k] = fmaf(c3, h2f(v3[k]), acc[k]);
            }
        }
    }

#pragma unroll
    for (int k = 0; k < 8; k++) acc[k] += __shfl(acc[k], lane ^ 32);

    if (mode == 0) {
        float v[8];
        float sum = 0.f, sq = 0.f;
#pragma unroll
        for (int k = 0; k < 8; k++) {
            v[k] = fmaxf(acc[k], 0.f);
            sum += v[k];
            sq  += v[k] * v[k];
        }
#pragma unroll
        for (int off = 16; off >= 1; off >>= 1) {
            sum += __shfl_xor(sum, off);
            sq  += __shfl_xor(sq, off);
        }
        float mu = sum * (1.f / 256.f);
        float var = fmaxf(sq * (1.f / 256.f) - mu * mu, 0.f);
        float rstd = rsqrtf(var + LN_EPS_W);
        float4 ga = *(const float4*)(g + col);
        float4 gb = *(const float4*)(g + col + 4);
        float4 ba = *(const float4*)(b + col);
        float4 bb = *(const float4*)(b + col + 4);
        float gg[8]  = {ga.x, ga.y, ga.z, ga.w, gb.x, gb.y, gb.z, gb.w};
        float bbv[8] = {ba.x, ba.y, ba.z, ba.w, bb.x, bb.y, bb.z, bb.w};
        float4 la = *(const float4*)(attlN + col);
        float4 lb = *(const float4*)(attlN + col + 4);
        float4 ra = *(const float4*)(attrN + col);
        float4 rb = *(const float4*)(attrN + col + 4);
        float ll[8] = {la.x, la.y, la.z, la.w, lb.x, lb.y, lb.z, lb.w};
        float rr[8] = {ra.x, ra.y, ra.z, ra.w, rb.x, rb.y, rb.z, rb.w};
        float pl = 0.f, pr = 0.f;
        u16x8 o;
#pragma unroll
        for (int k = 0; k < 8; k++) {
            float val = (v[k] - mu) * rstd * gg[k] + bbv[k];
            o[k] = f2h(val);
            pl += val * ll[k];
            pr += val * rr[k];
        }
#pragma unroll
        for (int off = 16; off >= 1; off >>= 1) {
            pl += __shfl_xor(pl, off);
            pr += __shfl_xor(pr, off);
        }
        if (lane == 0) { alOut[w] = pl; ar[w] = pr; }
        if (half == 0) *(u16x8*)(xout + (long)w * H_DIM + col) = o;
    } else {
        float p[N_CLS];
#pragma unroll
        for (int c = 0; c < N_CLS; c++) {
            const float* wr = Wl + c * H_DIM + col;
            float4 wa = *(const float4*)(wr);
            float4 wb = *(const float4*)(wr + 4);
            p[c] = acc[0] * wa.x + acc[1] * wa.y + acc[2] * wa.z + acc[3] * wa.w
                 + acc[4] * wb.x + acc[5] * wb.y + acc[6] * wb.z + acc[7] * wb.w;
        }
#pragma unroll
        for (int off = 16; off >= 1; off >>= 1) {
#pragma unroll
            for (int c = 0; c < N_CLS; c++) p[c] += __shfl_xor(p[c], off);
        }
        if (lane == 0) {
            float e[N_CLS];
            float m = -1e30f;
#pragma unroll
            for (int c = 0; c < N_CLS; c++) {
                e[c] = p[c] + bl[c];
                m = fmaxf(m, e[c]);
            }
            float sx = 0.f;
#pragma unroll
            for (int c = 0; c < N_CLS; c++) sx += expf(e[c] - m);
            float lse = logf(sx);
#pragma unroll
            for (int c = 0; c < N_CLS; c++) {
                outF[(long)w * N_CLS + c] = e[c];
                outF[(long)N_NODES * N_CLS + (long)w * N_CLS + c] = e[c] - m - lse;
            }
        }
    }
}

extern "C" void kernel_launch(void* const* d_in, const int* in_sizes, int n_in,
                              void* d_out, int out_size, void* d_ws, size_t ws_size,
                              hipStream_t stream) {
    const float* x_in   = (const float*)d_in[0];
    const int*   ei     = (const int*)d_in[1];     // [2][E] planar int32
    const float* W_init = (const float*)d_in[2];
    const float* b_init = (const float*)d_in[3];
    const float* att_l  = (const float*)d_in[4];
    const float* att_r  = (const float*)d_in[5];
    const float* ln_g   = (const float*)d_in[6];
    const float* ln_b   = (const float*)d_in[7];
    const float* W_last = (const float*)d_in[8];
    const float* b_last = (const float*)d_in[9];
    float* out = (float*)d_out;

    // workspace layout (80,802,112 B total)
    const size_t OFF_X0  = 0;                  // 25,600,000
    const size_t OFF_XA  = 25600000;           // 25,600,000
    const size_t OFF_XB  = 51200000;           // 25,600,000
    const size_t OFF_AL  = 76800000;           //    200,000 (W16 overlays AL/AR during init)
    const size_t OFF_AR  = 77000000;           //    200,000
    const size_t OFF_DEG = 77200000;           //    200,000 (al2 after CSR build)
    const size_t OFF_RP  = 77400000;           //    200,064
    const size_t OFF_SRC = 77600064;           //  3,200,000
    const size_t OFF_BS  = 80800064;           //      1,024
    const size_t OFF_BO  = 80801088;           //      1,024
    const size_t WS_NEED = 80802112;

    if (ws_size < WS_NEED) {
        sentinel_kernel<<<(out_size + 255) / 256, 256, 0, stream>>>(out, out_size);
        return;
    }

    char* ws = (char*)d_ws;
    u16* x0  = (u16*)(ws + OFF_X0);
    u16* xA  = (u16*)(ws + OFF_XA);
    u16* xB  = (u16*)(ws + OFF_XB);
    f16* W16 = (f16*)(ws + OFF_AL);
    float* al  = (float*)(ws + OFF_AL);
    float* ar  = (float*)(ws + OFF_AR);
    float* al2 = (float*)(ws + OFF_DEG);
    int* deg     = (int*)(ws + OFF_DEG);
    int* row_ptr = (int*)(ws + OFF_RP);
    int* srcS    = (int*)(ws + OFF_SRC);
    int* bsum    = (int*)(ws + OFF_BS);
    int* boff    = (int*)(ws + OFF_BO);

    const int* e_src = ei;
    const int* e_dst = ei + N_EDGES;

    // --- CSR build (by dst), two-level scan ---
    int zb = (N_NODES + 255) / 256;
    zero_kernel<<<zb, 256, 0, stream>>>(deg, N_NODES);
    int eb = (N_EDGES + 255) / 256;
    hist_kernel<<<eb, 256, 0, stream>>>(e_dst, deg, N_EDGES);
    scan_a<<<SCAN_NB, SCAN_B, 0, stream>>>(deg, row_ptr, bsum);
    scan_b<<<1, SCAN_B, 0, stream>>>(bsum, boff, row_ptr);
    scan_c<<<SCAN_NB, SCAN_B, 0, stream>>>(row_ptr, boff);
    scatter_kernel<<<eb, 256, 0, stream>>>(e_src, e_dst, row_ptr, deg, srcS, N_EDGES);

    // --- init linear: W convert + MFMA GEMM (X converted in-kernel) ---
    convert_w<<<(H_DIM * K_PAD) / 256, 256, 0, stream>>>(W_init, W16);
    mfma_gemm3<<<(N_NODES + 63) / 64, 256, 0, stream>>>(x_in, W16, b_init, x0);

    // --- al/ar for layer 0 ---
    int nb = (N_NODES * 64 + 255) / 256;   // one wave per node
    alar_kernel<<<nb, 256, 0, stream>>>(x0, att_l, att_r, al, ar, N_NODES);

    // --- layers 0-2 (LN mode), layer 3 (fused final) ---
    const u16* bufs_in[4]   = {x0, xA, xB, xA};
    u16* bufs_out[4]        = {xA, xB, xA, xB};   // [3] unused
    const float* al_in[4]   = {al, al2, al, al2};
    float* al_out[4]        = {al2, al, al2, al};
    for (int i = 0; i < 4; i++) {
        int nxt = (i < 3) ? (i + 1) : i;
        layer_kernel3<<<nb, 256, 0, stream>>>(bufs_in[i], x0, al_in[i], al_out[i], ar,
                                              row_ptr, srcS,
                                              ln_g + i * H_DIM, ln_b + i * H_DIM,
                                              att_l + nxt * H_DIM, att_r + nxt * H_DIM,
                                              bufs_out[i], W_last, b_last, out,
                                              N_NODES, (i < 3) ? 0 : 1);
    }
}